// Round 13
// baseline (189.603 us; speedup 1.0000x reference)
//
#include <hip/hip_runtime.h>
#include <hip/hip_bf16.h>
#include <hip/hip_fp16.h>

typedef unsigned short ushort_t;
typedef short short8_t __attribute__((ext_vector_type(8)));
typedef _Float16 half8_t __attribute__((ext_vector_type(8)));
typedef _Float16 h2 __attribute__((ext_vector_type(2)));
typedef float f32x4 __attribute__((ext_vector_type(4)));
typedef float f32x16 __attribute__((ext_vector_type(16)));

#define NBATCH 16
#define SEQ    60
#define NSTK   50
#define HID    128
#define G3     384
#define NIMG   800
#define IH     64
#define IW     60
#define P1H    32
#define P1W    30
#define P2C    64
#define FCIN   15360

// ---- workspace layout (float offsets) ----
#define OFF_WHHF   0u          // 49152 ushort  = 24576 f   (GRU W_hh bf16 frags)
#define OFF_WPREP  24576u      // 18432 ushort  = 9216 f    (conv2 W f16 A-frags)
#define OFF_WFC1   33792u      // 983040 ushort = 491520 f  (fc1 W bf16 frags)
#define OFF_GI     525312u     // 368640 f
#define OFF_HLAST  893952u     // 2048 f
#define OFF_POOL2  896000u     // 800*15360 bf16 = 6144000 f
#define OFF_FC2O   7040000u    // 102400 f
#define OFF_PART   7142400u    // 16*800*64 = 819200 f
#define OFF_W1H    7961600u    // 160 uint (144 w1 half2 pairs + 16 c1b half2)
#define WS_FLOATS  7961760u    // ~31.8 MB

// swizzle element counts for k_pre
#define E_WHH  49152
#define E_WPR  18432
#define E_FC1  983040
#define E_W1H  160
#define E_TOT  (E_WHH + E_WPR + E_FC1 + E_W1H)   // 1050784 -> 2737 blocks of 384

// ------------- shared-memory layouts -------------
struct __align__(16) ConvS {
    ushort_t pool1t[18][4][32][8];     // 36864 B  f16 bits, [ly][cg][xs][ch8]
    union {
        float    imgp[35][60];         //  8400 B  (conv1 phase)
        ushort_t pool2s[64][120];      // 15360 B  (conv2 staging, bf16)
    } u;
};                                      // 52224 B
struct __align__(16) GruS {
    ushort_t hb[2][16 * 136];          // 8704 B, double-buffered h (bf16)
};
#define SMEM_BYTES 52224

__device__ __forceinline__ float fast_sig(float x) {
    const float e = __expf(-x);
    return __builtin_amdgcn_rcpf(1.f + e);
}
__device__ __forceinline__ float fast_tanh(float x) {
    const float xc = fmaxf(fminf(x, 15.f), -15.f);
    const float e = __expf(2.f * xc);
    return (e - 1.f) * __builtin_amdgcn_rcpf(e + 1.f);
}
__device__ __forceinline__ h2 hmax2v(h2 a, h2 b) {      // lowers to v_pk_max_f16
    h2 r;
    r[0] = a[0] > b[0] ? a[0] : b[0];
    r[1] = a[1] > b[1] ? a[1] : b[1];
    return r;
}

// ---------------- k_pre: GI (blocks 0..959) + weight swizzles (960..) ----------------
__global__ __launch_bounds__(384) void k_pre(const float* __restrict__ xnum,
                                             const float* __restrict__ wih,
                                             const float* __restrict__ bih,
                                             const float* __restrict__ whh,
                                             const float* __restrict__ c2w,
                                             const float* __restrict__ fc1w,
                                             const float* __restrict__ c1w,
                                             const float* __restrict__ c1b,
                                             float* __restrict__ GI,
                                             ushort_t* __restrict__ whhf,
                                             ushort_t* __restrict__ wprep,
                                             ushort_t* __restrict__ wfc1,
                                             unsigned int* __restrict__ w1h)
{
    const int bid = blockIdx.x;
    if (bid < 960) {
        const int s = bid >> 4, b = bid & 15;
        const int j = threadIdx.x;
        const float* xr = xnum + (size_t)(b * SEQ + s) * NSTK;   // block-uniform -> scalar loads
        const float* wr = wih + (size_t)j * NSTK;
        float a = bih[j];
        #pragma unroll 10
        for (int k = 0; k < NSTK; ++k) a = fmaf(xr[k], wr[k], a);
        GI[((size_t)s * 16 + b) * G3 + j] = a;
        return;
    }
    const int idx = (bid - 960) * 384 + threadIdx.x;
    if (idx < E_WHH) {
        const int e = idx;                  // (((jt*4+ks)*64 + l)*8 + i)  bf16 (GRU)
        const int i = e & 7, l = (e >> 3) & 63, ksj = e >> 9;
        const int ks = ksj & 3, jt = ksj >> 2;
        const int j = jt * 16 + (l & 15);
        const int k = ks * 32 + ((l >> 4) << 3) + i;
        __hip_bfloat16 hv = __float2bfloat16(whh[j * HID + k]);
        whhf[e] = *(ushort_t*)&hv;
    } else if (idx < E_WHH + E_WPR) {
        const int e = idx - E_WHH;          // conv2 A-frags, F16
        const int i = e & 7, l = (e >> 3) & 63, rest = e >> 9;
        const int ks = rest & 1, mt = rest >> 1;
        const int tap = mt % 9, mm = mt / 9;
        const int oc = mm * 32 + (l & 31);
        const int ic = ks * 16 + ((l >> 5) << 3) + i;
        const _Float16 hv = (_Float16)c2w[((size_t)oc * 32 + ic) * 9 + tap];
        wprep[e] = *(const ushort_t*)&hv;
    } else if (idx < E_WHH + E_WPR + E_FC1) {
        const int e = idx - (E_WHH + E_WPR); // fc1 B-frags bf16
        const int i = e & 7, l = (e >> 3) & 63, rest = e >> 9;
        const int n = rest & 3, T = rest >> 2;
        const int oc = n * 16 + (l & 15);
        const int k = T * 32 + ((l >> 4) << 3) + i;
        __hip_bfloat16 hv = __float2bfloat16(fc1w[(size_t)oc * FCIN + k]);
        wfc1[e] = *(ushort_t*)&hv;
    } else if (idx < E_TOT) {
        const int e = idx - (E_WHH + E_WPR + E_FC1);  // conv1 f16-pair weights + bias
        if (e < 144) {
            const int p = e / 9, tap = e - p * 9;     // pair p -> ch (p>>2)*8+(p&3)*2
            const int ch0 = (p >> 2) * 8 + (p & 3) * 2;
            const _Float16 lo = (_Float16)c1w[ch0 * 9 + tap];
            const _Float16 hi = (_Float16)c1w[(ch0 + 1) * 9 + tap];
            w1h[p * 9 + tap] = ((unsigned)*(const ushort_t*)&hi << 16) | *(const ushort_t*)&lo;
        } else {
            const int p = e - 144;
            const int ch0 = (p >> 2) * 8 + (p & 3) * 2;
            const _Float16 lo = (_Float16)c1b[ch0];
            const _Float16 hi = (_Float16)c1b[ch0 + 1];
            w1h[144 + p] = ((unsigned)*(const ushort_t*)&hi << 16) | *(const ushort_t*)&lo;
        }
    }
}

// ------------- k_cnn: 1600 blocks, one image HALF each (pure CNN) -------------
__global__ __launch_bounds__(512, 2) void k_cnn(const float* __restrict__ x_img,
                                                const unsigned int* __restrict__ w1h,
                                                const float* __restrict__ c2b,
                                                const ushort_t* __restrict__ wprep,
                                                ushort_t* __restrict__ pool2)
{
    extern __shared__ char smraw[];
    const int tid = threadIdx.x;
    const int bid = blockIdx.x;

    ConvS* c = (ConvS*)smraw;
    const int img  = bid >> 1;
    const int half = bid & 1;
    const float* xim = x_img + (size_t)img * (IH * IW);
    const int rowbase = 29 * half;              // first image row in LDS

    // zero unwritten halo row (ly: half0->0, half1->17) + x halo cols 0,31
    {
        const short8_t z = {0, 0, 0, 0, 0, 0, 0, 0};
        const int zrow = half ? 17 : 0;
        if (tid < 128) {
            const int cg = tid >> 5, xs = tid & 31;
            *(short8_t*)&c->pool1t[zrow][cg][xs][0] = z;
        } else if (tid < 272) {
            const int q = tid - 128;
            const int ly = q / 8, cg = (q >> 1) & 3, xs = (q & 1) * 31;
            *(short8_t*)&c->pool1t[ly][cg][xs][0] = z;
        }
    }
    // copy 35 image rows to LDS (float4: 525 > 512 -> strided loop)
    {
        const f32x4* src = (const f32x4*)(xim + rowbase * IW);
        f32x4* dst = (f32x4*)c->u.imgp;
        for (int i = tid; i < 525; i += 512) dst[i] = src[i];
    }
    __syncthreads();

    // ---- conv1+relu+pool1 (packed f16): 17 pool rows x 30 px = 510 jobs ----
    if (tid < 510) {
        const int gj = tid / 30, px = tid - gj * 30;
        const int g = half * 15 + gj;
        const int ly = gj + 1 - half;
        const h2 z2 = {(_Float16)0.f, (_Float16)0.f};
        h2 patch2[4][4];
        #pragma unroll
        for (int yy = 0; yy < 4; ++yy) {
            const int giy = 2 * g - 1 + yy;
            const int liy = giy - rowbase;
            #pragma unroll
            for (int xx = 0; xx < 4; ++xx) {
                const int ix = 2 * px - 1 + xx;
                const float v = (giy >= 0 && giy < IH && ix >= 0 && ix < IW)
                                    ? c->u.imgp[liy][ix] : 0.f;
                const _Float16 vh = (_Float16)v;
                h2 p2; p2[0] = vh; p2[1] = vh;
                patch2[yy][xx] = p2;
            }
        }
        #pragma unroll
        for (int cg = 0; cg < 4; ++cg) {
            unsigned int ov[4];
            #pragma unroll
            for (int pr = 0; pr < 4; ++pr) {
                const int p = cg * 4 + pr;
                h2 wv[9];
                #pragma unroll
                for (int t = 0; t < 9; ++t) {          // uniform -> scalar loads
                    const unsigned int wu = w1h[p * 9 + t];
                    wv[t] = *(const h2*)&wu;
                }
                h2 a00 = z2, a01 = z2, a10 = z2, a11 = z2;
                #pragma unroll
                for (int ky = 0; ky < 3; ++ky)
                    #pragma unroll
                    for (int kx = 0; kx < 3; ++kx) {
                        const h2 wt = wv[ky * 3 + kx];
                        a00 = wt * patch2[ky][kx]     + a00;   // v_pk_fma_f16
                        a01 = wt * patch2[ky][kx + 1] + a01;
                        a10 = wt * patch2[ky + 1][kx] + a10;
                        a11 = wt * patch2[ky + 1][kx + 1] + a11;
                    }
                const unsigned int bu = w1h[144 + p];
                const h2 bia2 = *(const h2*)&bu;
                h2 m = hmax2v(hmax2v(a00, a01), hmax2v(a10, a11));
                h2 r = hmax2v(m + bia2, z2);
                ov[pr] = *(unsigned int*)&r;
            }
            *(uint4*)&c->pool1t[ly][cg][px + 1][0] = *(uint4*)ov;
        }
    }
    __syncthreads();   // conv1 done; imgp dead -> pool2s reuse

    // ---- conv2 f16 MFMA 32x32x16 implicit GEMM, staged flush ----
    {
        const int w  = tid >> 6, l = tid & 63;
        const int m  = w & 1;
        const int hi = l >> 5;
        const int col = l & 31;

        half8_t af[9][2];
        #pragma unroll
        for (int tap = 0; tap < 9; ++tap)
            #pragma unroll
            for (int ks = 0; ks < 2; ++ks)
                af[tap][ks] = *(const half8_t*)&wprep[(((m * 9 + tap) * 2 + ks) * 64 + l) * 8];
        float bia[16];
        #pragma unroll
        for (int r = 0; r < 16; ++r)
            bia[r] = c2b[m * 32 + (r & 3) + 8 * (r >> 2) + 4 * hi];

        const bool wr = ((col & 1) == 0) && (col < 30);
        const int px = col >> 1;

        #pragma unroll
        for (int yy = 0; yy < 2; ++yy) {
            const int ypl = (w >> 1) + yy * 4;           // 0..7 local pooled row
            f32x16 a0, a1;
            #pragma unroll
            for (int r = 0; r < 16; ++r) { a0[r] = 0.f; a1[r] = 0.f; }
            #pragma unroll
            for (int ro = 0; ro < 4; ++ro) {
                const int ly = 2 * ypl + ro;             // 0..17, halo rows pre-zeroed
                half8_t bf[3][2];
                #pragma unroll
                for (int kx = 0; kx < 3; ++kx)
                    #pragma unroll
                    for (int ks = 0; ks < 2; ++ks)
                        bf[kx][ks] = *(const half8_t*)&c->pool1t[ly][ks * 2 + hi][kx + col][0];
                if (ro < 3) {
                    #pragma unroll
                    for (int kx = 0; kx < 3; ++kx)
                        #pragma unroll
                        for (int ks = 0; ks < 2; ++ks)
                            a0 = __builtin_amdgcn_mfma_f32_32x32x16_f16(af[ro * 3 + kx][ks], bf[kx][ks], a0, 0, 0, 0);
                }
                if (ro >= 1) {
                    #pragma unroll
                    for (int kx = 0; kx < 3; ++kx)
                        #pragma unroll
                        for (int ks = 0; ks < 2; ++ks)
                            a1 = __builtin_amdgcn_mfma_f32_32x32x16_f16(af[(ro - 1) * 3 + kx][ks], bf[kx][ks], a1, 0, 0, 0);
                }
            }
            #pragma unroll
            for (int r = 0; r < 16; ++r) {
                float v = fmaxf(a0[r], a1[r]);
                v = fmaxf(v, __shfl_xor(v, 1, 64));
                v = fmaxf(v + bia[r], 0.f);
                if (wr) {
                    const int oc = m * 32 + (r & 3) + 8 * (r >> 2) + 4 * hi;
                    __hip_bfloat16 hv = __float2bfloat16(v);
                    c->u.pool2s[oc][ypl * 15 + px] = *(ushort_t*)&hv;
                }
            }
        }
        __syncthreads();   // staging complete
        // coalesced flush: 960 int4 = 64 oc x 15 int4 (this half's 120 ushorts/oc)
        {
            int4* dst = (int4*)(pool2 + (size_t)img * FCIN);
            const int4* src = (const int4*)c->u.pool2s;
            #pragma unroll
            for (int jj = 0; jj < 2; ++jj) {
                const int i = tid + jj * 512;
                if (i < 960) {
                    const int oc = i / 15, cc = i - oc * 15;
                    dst[oc * 30 + half * 15 + cc] = src[i];
                }
            }
        }
    }
}

// -------- fc1 split-K MFMA: 50 M-tiles x 16 K-splits, part[ks][img][oc] --------
__global__ __launch_bounds__(256) void k_fc1(const ushort_t* __restrict__ pool2,
                                             const ushort_t* __restrict__ wfc1,
                                             float* __restrict__ part)
{
    const int mt = blockIdx.x >> 4;             // 0..49 (16 images)
    const int ks = blockIdx.x & 15;             // K-split of 960
    const int n = threadIdx.x >> 6, l = threadIdx.x & 63;   // wave = oc tile
    const int arow = l & 15, kq = l >> 4;
    const int img16 = mt * 16;
    const ushort_t* Ab = pool2 + (size_t)(img16 + arow) * FCIN + ks * 960 + kq * 8;
    const ushort_t* Bb = wfc1 + ((size_t)(ks * 30 * 4 + n) * 64 + l) * 8;
    f32x4 acc0 = {0.f, 0.f, 0.f, 0.f}, acc1 = {0.f, 0.f, 0.f, 0.f};
    #pragma unroll 10
    for (int t = 0; t < 30; t += 2) {
        const short8_t aA = *(const short8_t*)(Ab + (size_t)t * 32);
        const short8_t bA = *(const short8_t*)(Bb + (size_t)t * 2048);
        const short8_t aB = *(const short8_t*)(Ab + (size_t)(t + 1) * 32);
        const short8_t bB = *(const short8_t*)(Bb + (size_t)(t + 1) * 2048);
        acc0 = __builtin_amdgcn_mfma_f32_16x16x32_bf16(aA, bA, acc0, 0, 0, 0);
        acc1 = __builtin_amdgcn_mfma_f32_16x16x32_bf16(aB, bB, acc1, 0, 0, 0);
    }
    float* dst = &part[((size_t)ks * NIMG + img16 + kq * 4) * 64 + n * 16 + arow];
    #pragma unroll
    for (int r = 0; r < 4; ++r)
        dst[(size_t)r * 64] = acc0[r] + acc1[r];
}

__device__ __forceinline__ float wave_sum(float v) {
    #pragma unroll
    for (int o = 32; o > 0; o >>= 1) v += __shfl_xor(v, o, 64);
    return v;
}
__device__ __forceinline__ float wave_max(float v) {
    #pragma unroll
    for (int o = 32; o > 0; o >>= 1) v = fmaxf(v, __shfl_xor(v, o, 64));
    return v;
}

// -------- k_postgru: blocks 0..99 = fc1-reduce + heads; block 100 = GRU --------
__global__ __launch_bounds__(512, 2) void k_postgru(const float* __restrict__ part,
                                                    const float* __restrict__ fc1b,
                                                    const float* __restrict__ fbw,
                                                    const float* __restrict__ fbb,
                                                    const float* __restrict__ fc2w,
                                                    const float* __restrict__ fc2b,
                                                    const float* __restrict__ GI,
                                                    const ushort_t* __restrict__ whhf,
                                                    const float* __restrict__ bhh,
                                                    float* __restrict__ out,
                                                    float* __restrict__ fc2o,
                                                    float* __restrict__ hlast)
{
    __shared__ __align__(16) char sm[8704];
    const int tid = threadIdx.x;

    if (blockIdx.x == 100) {
        // ===== GRU: one barrier/step, gates fully in-register (R11 structure) =====
        GruS* g = (GruS*)sm;
        const int w = tid >> 6, l = tid & 63;
        const int arow = l & 15, kq = l >> 4;          // A-frag: row=b index, k-chunk
        const int hh = w * 16 + (l & 15);              // D col -> hh
        const int b0 = (l >> 4) * 4;                   // D rows b0..b0+3
        short8_t wfr[3][4];
        #pragma unroll
        for (int g3 = 0; g3 < 3; ++g3)
            #pragma unroll
            for (int ks = 0; ks < 4; ++ks)
                wfr[g3][ks] = *(const short8_t*)&whhf[((((g3 * 8 + w) * 4 + ks) * 64 + l) * 8)];
        const float bhr = bhh[hh];
        const float bhz = bhh[128 + hh];
        const float bhn = bhh[256 + hh];
        float h[4] = {0.f, 0.f, 0.f, 0.f};
        for (int i = tid; i < 1088; i += 512) ((unsigned int*)g->hb[0])[i] = 0u;
        __syncthreads();

        int cur = 0;
        for (int s = 0; s < SEQ; ++s) {
            const float* gis = GI + ((size_t)s * 16 + b0) * G3 + hh;
            float cr[4], cz[4], cn[4];
            #pragma unroll
            for (int r = 0; r < 4; ++r) {
                cr[r] = gis[r * G3];
                cz[r] = gis[r * G3 + 128];
                cn[r] = gis[r * G3 + 256];
            }
            f32x4 ar = {0.f, 0.f, 0.f, 0.f};
            f32x4 az = {0.f, 0.f, 0.f, 0.f};
            f32x4 an = {0.f, 0.f, 0.f, 0.f};
            #pragma unroll
            for (int ks = 0; ks < 4; ++ks) {
                const short8_t af = *(const short8_t*)&g->hb[cur][arow * 136 + ks * 32 + kq * 8];
                ar = __builtin_amdgcn_mfma_f32_16x16x32_bf16(af, wfr[0][ks], ar, 0, 0, 0);
                az = __builtin_amdgcn_mfma_f32_16x16x32_bf16(af, wfr[1][ks], az, 0, 0, 0);
                an = __builtin_amdgcn_mfma_f32_16x16x32_bf16(af, wfr[2][ks], an, 0, 0, 0);
            }
            const int nxt = cur ^ 1;
            #pragma unroll
            for (int r = 0; r < 4; ++r) {
                const float rg = fast_sig(cr[r] + ar[r] + bhr);
                const float zg = fast_sig(cz[r] + az[r] + bhz);
                const float ng = fast_tanh(cn[r] + rg * (an[r] + bhn));
                h[r] = (1.f - zg) * ng + zg * h[r];
                __hip_bfloat16 t = __float2bfloat16(h[r]);
                g->hb[nxt][(b0 + r) * 136 + hh] = *(ushort_t*)&t;
            }
            __syncthreads();
            cur = nxt;
        }
        #pragma unroll
        for (int r = 0; r < 4; ++r) hlast[(b0 + r) * HID + hh] = h[r];
        return;
    }

    // ---- fc1 partial reduce + relu + binary head + fc2 (8 imgs/block) ----
    float (*flc)[64] = (float(*)[64])sm;
    const int im8 = tid >> 6;                   // 0..7 == wave id
    const int tl = tid & 63;                    // oc
    const int img = blockIdx.x * 8 + im8;
    float s = fc1b[tl];
    #pragma unroll
    for (int ks = 0; ks < 16; ++ks) s += part[((size_t)ks * NIMG + img) * 64 + tl];
    const float f = fmaxf(s, 0.f);
    flc[im8][tl] = f;
    const float bs = wave_sum(f * fbw[tl]);
    if (tl == 0) out[800 + img] = 1.f / (1.f + expf(-(bs + fbb[0])));
    __syncthreads();
    #pragma unroll
    for (int q = 0; q < 2; ++q) {
        const int j = tl + q * 64;
        float a2 = fc2b[j];
        #pragma unroll 8
        for (int k = 0; k < 64; ++k) a2 = fmaf(flc[im8][k], fc2w[j * 64 + k], a2);
        fc2o[(size_t)img * 128 + j] = a2;
    }
}

// ---------------- fusion + softmax + 32-iter water-filling rebalance --------
__global__ __launch_bounds__(64) void k_final(const float* __restrict__ hlast,
                                              const float* __restrict__ fc2o,
                                              const float* __restrict__ gw,
                                              const float* __restrict__ gb,
                                              const float* __restrict__ fw,
                                              const float* __restrict__ fb,
                                              const float* __restrict__ finw,
                                              const float* __restrict__ finb,
                                              float* __restrict__ out)
{
    const int b = blockIdx.x, t = threadIdx.x;
    __shared__ float cf[128], nf[64], fu[64];
    #pragma unroll
    for (int jj = 0; jj < 2; ++jj) {
        const int j = t + jj * 64;
        float s = 0.f;
        for (int n = 0; n < NSTK; ++n) s += fc2o[(size_t)(b * NSTK + n) * 128 + j];
        cf[j] = s * (1.0f / 50.0f);
    }
    float s = 0.f;
    if (t < NSTK) {
        s = gb[t];
        for (int k = 0; k < HID; ++k) s = fmaf(hlast[b * HID + k], gw[t * HID + k], s);
    }
    nf[t] = (t < NSTK) ? s : 0.f;
    __syncthreads();
    float f = fb[t];
    for (int k = 0; k < NSTK; ++k) f = fmaf(nf[k], fw[t * 178 + k], f);
    for (int k = 0; k < 128; ++k) f = fmaf(cf[k], fw[t * 178 + 50 + k], f);
    fu[t] = fmaxf(f, 0.f);
    __syncthreads();
    float L = -3.4e38f;
    if (t < NSTK) {
        L = finb[t];
        for (int k = 0; k < 64; ++k) L = fmaf(fu[k], finw[t * 64 + k], L);
    }
    const float m = wave_max(L);
    const float e = (t < NSTK) ? expf(L - m) : 0.f;
    const float se = wave_sum(e);
    const float wv = e / se;
    float old = wv;
    float wc = fminf(fmaxf(wv, 0.f), 0.1f);
    for (int it = 0; it < 32; ++it) {
        const float leftover = wave_sum(old - wc);
        const bool mask = (wc != 0.1f);
        const float ssum = wave_sum(mask ? wc : 0.f);
        const float gift = (mask && ssum > 0.f) ? leftover * wc / ssum : 0.f;
        old = wc + gift;
        wc = fminf(fmaxf(old, 0.f), 0.1f);
    }
    if (t < NSTK) out[b * NSTK + t] = wc;
}

// ---------------------------------------------------------------------------
extern "C" void kernel_launch(void* const* d_in, const int* in_sizes, int n_in,
                              void* d_out, int out_size, void* d_ws, size_t ws_size,
                              hipStream_t stream)
{
    const float* x_num = (const float*)d_in[0];
    const float* x_img = (const float*)d_in[1];
    const float* c1w  = (const float*)d_in[2];
    const float* c1b  = (const float*)d_in[3];
    const float* c2w  = (const float*)d_in[4];
    const float* c2b  = (const float*)d_in[5];
    const float* fc1w = (const float*)d_in[6];
    const float* fc1b = (const float*)d_in[7];
    const float* fbw  = (const float*)d_in[8];
    const float* fbb  = (const float*)d_in[9];
    const float* fc2w = (const float*)d_in[10];
    const float* fc2b = (const float*)d_in[11];
    const float* wih  = (const float*)d_in[12];
    const float* whh  = (const float*)d_in[13];
    const float* bih  = (const float*)d_in[14];
    const float* bhh  = (const float*)d_in[15];
    const float* gw   = (const float*)d_in[16];
    const float* gb   = (const float*)d_in[17];
    const float* fw   = (const float*)d_in[18];
    const float* fb   = (const float*)d_in[19];
    const float* finw = (const float*)d_in[20];
    const float* finb = (const float*)d_in[21];
    float* out = (float*)d_out;
    float* ws  = (float*)d_ws;
    if (ws_size < (size_t)WS_FLOATS * 4) return;

    ushort_t* whhf  = (ushort_t*)(ws + OFF_WHHF);
    ushort_t* wprep = (ushort_t*)(ws + OFF_WPREP);
    ushort_t* wfc1  = (ushort_t*)(ws + OFF_WFC1);
    float* GI       = ws + OFF_GI;
    float* hlast    = ws + OFF_HLAST;
    ushort_t* pool2 = (ushort_t*)(ws + OFF_POOL2);
    float* fc2o     = ws + OFF_FC2O;
    float* part     = ws + OFF_PART;
    unsigned int* w1h = (unsigned int*)(ws + OFF_W1H);

    (void)hipFuncSetAttribute(reinterpret_cast<const void*>(k_cnn),
                              hipFuncAttributeMaxDynamicSharedMemorySize, SMEM_BYTES);

    k_pre     <<<960 + 2737, 384, 0, stream>>>(x_num, wih, bih, whh, c2w, fc1w, c1w, c1b,
                                               GI, whhf, wprep, wfc1, w1h);
    k_cnn     <<<2 * NIMG, 512, SMEM_BYTES, stream>>>(x_img, w1h, c2b, wprep, pool2);
    k_fc1     <<<50 * 16, 256, 0, stream>>>(pool2, wfc1, part);
    k_postgru <<<101, 512, 0, stream>>>(part, fc1b, fbw, fbb, fc2w, fc2b,
                                        GI, whhf, bhh, out, fc2o, hlast);
    k_final   <<<NBATCH, 64, 0, stream>>>(hlast, fc2o, gw, gb, fw, fb, finw, finb, out);
}

// Round 14
// 143.576 us; speedup vs baseline: 1.3206x; 1.3206x over previous
//
#include <hip/hip_runtime.h>
#include <hip/hip_bf16.h>
#include <hip/hip_fp16.h>

typedef unsigned short ushort_t;
typedef short short8_t __attribute__((ext_vector_type(8)));
typedef _Float16 half8_t __attribute__((ext_vector_type(8)));
typedef _Float16 h2 __attribute__((ext_vector_type(2)));
typedef float f32x4 __attribute__((ext_vector_type(4)));
typedef float f32x16 __attribute__((ext_vector_type(16)));

#define NBATCH 16
#define SEQ    60
#define NSTK   50
#define HID    128
#define G3     384
#define NIMG   800
#define IH     64
#define IW     60
#define P1H    32
#define P1W    30
#define P2C    64
#define FCIN   15360

// ---- workspace layout (float offsets) ----
#define OFF_WHHF   0u          // 49152 ushort  = 24576 f   (GRU W_hh bf16 frags)
#define OFF_WPREP  24576u      // 18432 ushort  = 9216 f    (conv2 W f16 A-frags)
#define OFF_WFC1   33792u      // 983040 ushort = 491520 f  (fc1 W bf16 frags)
#define OFF_GI     525312u     // 368640 f
#define OFF_HLAST  893952u     // 2048 f
#define OFF_POOL2  896000u     // 800*15360 bf16 = 6144000 f
#define OFF_FC2O   7040000u    // 102400 f
#define OFF_PART   7142400u    // 16*800*64 = 819200 f
#define OFF_W1H    7961600u    // 160 uint (144 w1 half2 pairs + 16 c1b half2)
#define WS_FLOATS  7961760u    // ~31.8 MB

// swizzle element counts for k_pre
#define E_WHH  49152
#define E_WPR  18432
#define E_FC1  983040
#define E_W1H  160
#define E_TOT  (E_WHH + E_WPR + E_FC1 + E_W1H)   // 1050784 -> 2737 blocks of 384

// ------------- shared-memory layouts -------------
struct __align__(16) ConvS {
    ushort_t pool1t[18][4][32][8];     // 36864 B  f16 bits, [ly][cg][xs][ch8]
    ushort_t pool2s[64][120];          // 15360 B  (conv2 staging, bf16)
};                                      // 52224 B
struct __align__(16) GruS {
    ushort_t hb[2][16 * 136];          // 8704 B, double-buffered h (bf16)
};
#define SMEM_BYTES 52224

__device__ __forceinline__ float fast_sig(float x) {
    const float e = __expf(-x);
    return __builtin_amdgcn_rcpf(1.f + e);
}
__device__ __forceinline__ float fast_tanh(float x) {
    const float xc = fmaxf(fminf(x, 15.f), -15.f);
    const float e = __expf(2.f * xc);
    return (e - 1.f) * __builtin_amdgcn_rcpf(e + 1.f);
}
__device__ __forceinline__ h2 hmax2v(h2 a, h2 b) {      // lowers to v_pk_max_f16
    h2 r;
    r[0] = a[0] > b[0] ? a[0] : b[0];
    r[1] = a[1] > b[1] ? a[1] : b[1];
    return r;
}

// ---------------- k_pre: GI (blocks 0..959) + weight swizzles (960..) ----------------
__global__ __launch_bounds__(384) void k_pre(const float* __restrict__ xnum,
                                             const float* __restrict__ wih,
                                             const float* __restrict__ bih,
                                             const float* __restrict__ whh,
                                             const float* __restrict__ c2w,
                                             const float* __restrict__ fc1w,
                                             const float* __restrict__ c1w,
                                             const float* __restrict__ c1b,
                                             float* __restrict__ GI,
                                             ushort_t* __restrict__ whhf,
                                             ushort_t* __restrict__ wprep,
                                             ushort_t* __restrict__ wfc1,
                                             unsigned int* __restrict__ w1h)
{
    const int bid = blockIdx.x;
    if (bid < 960) {
        const int s = bid >> 4, b = bid & 15;
        const int j = threadIdx.x;
        const float* xr = xnum + (size_t)(b * SEQ + s) * NSTK;   // block-uniform -> scalar loads
        const float* wr = wih + (size_t)j * NSTK;
        float a = bih[j];
        #pragma unroll 10
        for (int k = 0; k < NSTK; ++k) a = fmaf(xr[k], wr[k], a);
        GI[((size_t)s * 16 + b) * G3 + j] = a;
        return;
    }
    const int idx = (bid - 960) * 384 + threadIdx.x;
    if (idx < E_WHH) {
        const int e = idx;                  // (((jt*4+ks)*64 + l)*8 + i)  bf16 (GRU)
        const int i = e & 7, l = (e >> 3) & 63, ksj = e >> 9;
        const int ks = ksj & 3, jt = ksj >> 2;
        const int j = jt * 16 + (l & 15);
        const int k = ks * 32 + ((l >> 4) << 3) + i;
        __hip_bfloat16 hv = __float2bfloat16(whh[j * HID + k]);
        whhf[e] = *(ushort_t*)&hv;
    } else if (idx < E_WHH + E_WPR) {
        const int e = idx - E_WHH;          // conv2 A-frags, F16
        const int i = e & 7, l = (e >> 3) & 63, rest = e >> 9;
        const int ks = rest & 1, mt = rest >> 1;
        const int tap = mt % 9, mm = mt / 9;
        const int oc = mm * 32 + (l & 31);
        const int ic = ks * 16 + ((l >> 5) << 3) + i;
        const _Float16 hv = (_Float16)c2w[((size_t)oc * 32 + ic) * 9 + tap];
        wprep[e] = *(const ushort_t*)&hv;
    } else if (idx < E_WHH + E_WPR + E_FC1) {
        const int e = idx - (E_WHH + E_WPR); // fc1 B-frags bf16
        const int i = e & 7, l = (e >> 3) & 63, rest = e >> 9;
        const int n = rest & 3, T = rest >> 2;
        const int oc = n * 16 + (l & 15);
        const int k = T * 32 + ((l >> 4) << 3) + i;
        __hip_bfloat16 hv = __float2bfloat16(fc1w[(size_t)oc * FCIN + k]);
        wfc1[e] = *(ushort_t*)&hv;
    } else if (idx < E_TOT) {
        const int e = idx - (E_WHH + E_WPR + E_FC1);  // conv1 f16-pair weights + bias
        if (e < 144) {
            const int p = e / 9, tap = e - p * 9;     // pair p -> ch (p>>2)*8+(p&3)*2
            const int ch0 = (p >> 2) * 8 + (p & 3) * 2;
            const _Float16 lo = (_Float16)c1w[ch0 * 9 + tap];
            const _Float16 hi = (_Float16)c1w[(ch0 + 1) * 9 + tap];
            w1h[p * 9 + tap] = ((unsigned)*(const ushort_t*)&hi << 16) | *(const ushort_t*)&lo;
        } else {
            const int p = e - 144;
            const int ch0 = (p >> 2) * 8 + (p & 3) * 2;
            const _Float16 lo = (_Float16)c1b[ch0];
            const _Float16 hi = (_Float16)c1b[ch0 + 1];
            w1h[144 + p] = ((unsigned)*(const ushort_t*)&hi << 16) | *(const ushort_t*)&lo;
        }
    }
}

// ------- mega: block 0 = GRU, blocks 1..1600 = one image HALF each -------
__global__ __launch_bounds__(512, 2) void k_mega(const float* __restrict__ x_img,
                                                 const unsigned int* __restrict__ w1h,
                                                 const float* __restrict__ c2b,
                                                 const ushort_t* __restrict__ wprep,
                                                 const float* __restrict__ GI,
                                                 const ushort_t* __restrict__ whhf,
                                                 const float* __restrict__ bhh,
                                                 ushort_t* __restrict__ pool2,
                                                 float* __restrict__ hlast)
{
    extern __shared__ char smraw[];
    const int tid = threadIdx.x;
    const int bid = blockIdx.x;

    if (bid == 0) {
        // ===== GRU: one barrier/step, gates fully in-register =====
        GruS* g = (GruS*)smraw;
        const int w = tid >> 6, l = tid & 63;
        const int arow = l & 15, kq = l >> 4;          // A-frag: row=b index, k-chunk
        const int hh = w * 16 + (l & 15);              // D col -> hh
        const int b0 = (l >> 4) * 4;                   // D rows b0..b0+3
        short8_t wfr[3][4];
        #pragma unroll
        for (int g3 = 0; g3 < 3; ++g3)
            #pragma unroll
            for (int ks = 0; ks < 4; ++ks)
                wfr[g3][ks] = *(const short8_t*)&whhf[((((g3 * 8 + w) * 4 + ks) * 64 + l) * 8)];
        const float bhr = bhh[hh];
        const float bhz = bhh[128 + hh];
        const float bhn = bhh[256 + hh];
        float h[4] = {0.f, 0.f, 0.f, 0.f};
        for (int i = tid; i < 1088; i += 512) ((unsigned int*)g->hb[0])[i] = 0u;
        __syncthreads();

        int cur = 0;
        for (int s = 0; s < SEQ; ++s) {
            const float* gis = GI + ((size_t)s * 16 + b0) * G3 + hh;
            float cr[4], cz[4], cn[4];
            #pragma unroll
            for (int r = 0; r < 4; ++r) {
                cr[r] = gis[r * G3];
                cz[r] = gis[r * G3 + 128];
                cn[r] = gis[r * G3 + 256];
            }
            f32x4 ar = {0.f, 0.f, 0.f, 0.f};
            f32x4 az = {0.f, 0.f, 0.f, 0.f};
            f32x4 an = {0.f, 0.f, 0.f, 0.f};
            #pragma unroll
            for (int ks = 0; ks < 4; ++ks) {
                const short8_t af = *(const short8_t*)&g->hb[cur][arow * 136 + ks * 32 + kq * 8];
                ar = __builtin_amdgcn_mfma_f32_16x16x32_bf16(af, wfr[0][ks], ar, 0, 0, 0);
                az = __builtin_amdgcn_mfma_f32_16x16x32_bf16(af, wfr[1][ks], az, 0, 0, 0);
                an = __builtin_amdgcn_mfma_f32_16x16x32_bf16(af, wfr[2][ks], an, 0, 0, 0);
            }
            const int nxt = cur ^ 1;
            #pragma unroll
            for (int r = 0; r < 4; ++r) {
                const float rg = fast_sig(cr[r] + ar[r] + bhr);
                const float zg = fast_sig(cz[r] + az[r] + bhz);
                const float ng = fast_tanh(cn[r] + rg * (an[r] + bhn));
                h[r] = (1.f - zg) * ng + zg * h[r];
                __hip_bfloat16 t = __float2bfloat16(h[r]);
                g->hb[nxt][(b0 + r) * 136 + hh] = *(ushort_t*)&t;
            }
            __syncthreads();
            cur = nxt;
        }
        #pragma unroll
        for (int r = 0; r < 4; ++r) hlast[(b0 + r) * HID + hh] = h[r];
        return;
    }

    // ================== CNN branch, one image HALF per block ==================
    ConvS* c = (ConvS*)smraw;
    const int img  = (bid - 1) >> 1;
    const int half = (bid - 1) & 1;
    const float* xim = x_img + (size_t)img * (IH * IW);

    // zero unwritten halo row (ly: half0->0, half1->17) + x halo cols 0,31
    {
        const short8_t z = {0, 0, 0, 0, 0, 0, 0, 0};
        const int zrow = half ? 17 : 0;
        if (tid < 128) {
            const int cg = tid >> 5, xs = tid & 31;
            *(short8_t*)&c->pool1t[zrow][cg][xs][0] = z;
        } else if (tid < 272) {
            const int q = tid - 128;
            const int ly = q / 8, cg = (q >> 1) & 3, xs = (q & 1) * 31;
            *(short8_t*)&c->pool1t[ly][cg][xs][0] = z;
        }
    }

    // ---- conv1+relu+pool1 (packed f16), patch direct from global (L2/L3) ----
    if (tid < 510) {
        const int gj = tid / 30, px = tid - gj * 30;
        const int g = half * 15 + gj;
        const int ly = gj + 1 - half;
        const h2 z2 = {(_Float16)0.f, (_Float16)0.f};
        h2 patch2[4][4];
        #pragma unroll
        for (int yy = 0; yy < 4; ++yy) {
            const int giy = 2 * g - 1 + yy;
            #pragma unroll
            for (int xx = 0; xx < 4; ++xx) {
                const int ix = 2 * px - 1 + xx;
                const float v = (giy >= 0 && giy < IH && ix >= 0 && ix < IW)
                                    ? xim[giy * IW + ix] : 0.f;
                const _Float16 vh = (_Float16)v;
                h2 p2; p2[0] = vh; p2[1] = vh;
                patch2[yy][xx] = p2;
            }
        }
        #pragma unroll
        for (int cg = 0; cg < 4; ++cg) {
            unsigned int ov[4];
            #pragma unroll
            for (int pr = 0; pr < 4; ++pr) {
                const int p = cg * 4 + pr;
                h2 wv[9];
                #pragma unroll
                for (int t = 0; t < 9; ++t) {          // uniform -> scalar loads
                    const unsigned int wu = w1h[p * 9 + t];
                    wv[t] = *(const h2*)&wu;
                }
                h2 a00 = z2, a01 = z2, a10 = z2, a11 = z2;
                #pragma unroll
                for (int ky = 0; ky < 3; ++ky)
                    #pragma unroll
                    for (int kx = 0; kx < 3; ++kx) {
                        const h2 wt = wv[ky * 3 + kx];
                        a00 = wt * patch2[ky][kx]     + a00;   // v_pk_fma_f16
                        a01 = wt * patch2[ky][kx + 1] + a01;
                        a10 = wt * patch2[ky + 1][kx] + a10;
                        a11 = wt * patch2[ky + 1][kx + 1] + a11;
                    }
                const unsigned int bu = w1h[144 + p];
                const h2 bia2 = *(const h2*)&bu;
                h2 m = hmax2v(hmax2v(a00, a01), hmax2v(a10, a11));
                h2 r = hmax2v(m + bia2, z2);
                ov[pr] = *(unsigned int*)&r;
            }
            *(uint4*)&c->pool1t[ly][cg][px + 1][0] = *(uint4*)ov;
        }
    }
    __syncthreads();   // pool1t ready

    // ---- conv2 f16 MFMA 32x32x16 implicit GEMM, staged flush ----
    {
        const int w  = tid >> 6, l = tid & 63;
        const int m  = w & 1;
        const int hi = l >> 5;
        const int col = l & 31;

        half8_t af[9][2];
        #pragma unroll
        for (int tap = 0; tap < 9; ++tap)
            #pragma unroll
            for (int ks = 0; ks < 2; ++ks)
                af[tap][ks] = *(const half8_t*)&wprep[(((m * 9 + tap) * 2 + ks) * 64 + l) * 8];
        float bia[16];
        #pragma unroll
        for (int r = 0; r < 16; ++r)
            bia[r] = c2b[m * 32 + (r & 3) + 8 * (r >> 2) + 4 * hi];

        const bool wr = ((col & 1) == 0) && (col < 30);
        const int px = col >> 1;

        #pragma unroll
        for (int yy = 0; yy < 2; ++yy) {
            const int ypl = (w >> 1) + yy * 4;           // 0..7 local pooled row
            f32x16 a0, a1;
            #pragma unroll
            for (int r = 0; r < 16; ++r) { a0[r] = 0.f; a1[r] = 0.f; }
            #pragma unroll
            for (int ro = 0; ro < 4; ++ro) {
                const int ly = 2 * ypl + ro;             // 0..17, halo rows pre-zeroed
                half8_t bf[3][2];
                #pragma unroll
                for (int kx = 0; kx < 3; ++kx)
                    #pragma unroll
                    for (int ks = 0; ks < 2; ++ks)
                        bf[kx][ks] = *(const half8_t*)&c->pool1t[ly][ks * 2 + hi][kx + col][0];
                if (ro < 3) {
                    #pragma unroll
                    for (int kx = 0; kx < 3; ++kx)
                        #pragma unroll
                        for (int ks = 0; ks < 2; ++ks)
                            a0 = __builtin_amdgcn_mfma_f32_32x32x16_f16(af[ro * 3 + kx][ks], bf[kx][ks], a0, 0, 0, 0);
                }
                if (ro >= 1) {
                    #pragma unroll
                    for (int kx = 0; kx < 3; ++kx)
                        #pragma unroll
                        for (int ks = 0; ks < 2; ++ks)
                            a1 = __builtin_amdgcn_mfma_f32_32x32x16_f16(af[(ro - 1) * 3 + kx][ks], bf[kx][ks], a1, 0, 0, 0);
                }
            }
            #pragma unroll
            for (int r = 0; r < 16; ++r) {
                float v = fmaxf(a0[r], a1[r]);
                v = fmaxf(v, __shfl_xor(v, 1, 64));
                v = fmaxf(v + bia[r], 0.f);
                if (wr) {
                    const int oc = m * 32 + (r & 3) + 8 * (r >> 2) + 4 * hi;
                    __hip_bfloat16 hv = __float2bfloat16(v);
                    c->pool2s[oc][ypl * 15 + px] = *(ushort_t*)&hv;
                }
            }
        }
        __syncthreads();   // staging complete
        // coalesced flush: 960 int4 = 64 oc x 15 int4 (this half's 120 ushorts/oc)
        {
            int4* dst = (int4*)(pool2 + (size_t)img * FCIN);
            const int4* src = (const int4*)c->pool2s;
            #pragma unroll
            for (int jj = 0; jj < 2; ++jj) {
                const int i = tid + jj * 512;
                if (i < 960) {
                    const int oc = i / 15, cc = i - oc * 15;
                    dst[oc * 30 + half * 15 + cc] = src[i];
                }
            }
        }
    }
}

// -------- fc1 split-K MFMA: 50 M-tiles x 16 K-splits, part[ks][img][oc] --------
__global__ __launch_bounds__(256) void k_fc1(const ushort_t* __restrict__ pool2,
                                             const ushort_t* __restrict__ wfc1,
                                             float* __restrict__ part)
{
    const int mt = blockIdx.x >> 4;             // 0..49 (16 images)
    const int ks = blockIdx.x & 15;             // K-split of 960
    const int n = threadIdx.x >> 6, l = threadIdx.x & 63;   // wave = oc tile
    const int arow = l & 15, kq = l >> 4;
    const int img16 = mt * 16;
    const ushort_t* Ab = pool2 + (size_t)(img16 + arow) * FCIN + ks * 960 + kq * 8;
    const ushort_t* Bb = wfc1 + ((size_t)(ks * 30 * 4 + n) * 64 + l) * 8;
    f32x4 acc0 = {0.f, 0.f, 0.f, 0.f}, acc1 = {0.f, 0.f, 0.f, 0.f};
    #pragma unroll 10
    for (int t = 0; t < 30; t += 2) {
        const short8_t aA = *(const short8_t*)(Ab + (size_t)t * 32);
        const short8_t bA = *(const short8_t*)(Bb + (size_t)t * 2048);
        const short8_t aB = *(const short8_t*)(Ab + (size_t)(t + 1) * 32);
        const short8_t bB = *(const short8_t*)(Bb + (size_t)(t + 1) * 2048);
        acc0 = __builtin_amdgcn_mfma_f32_16x16x32_bf16(aA, bA, acc0, 0, 0, 0);
        acc1 = __builtin_amdgcn_mfma_f32_16x16x32_bf16(aB, bB, acc1, 0, 0, 0);
    }
    float* dst = &part[((size_t)ks * NIMG + img16 + kq * 4) * 64 + n * 16 + arow];
    #pragma unroll
    for (int r = 0; r < 4; ++r)
        dst[(size_t)r * 64] = acc0[r] + acc1[r];
}

__device__ __forceinline__ float wave_sum(float v) {
    #pragma unroll
    for (int o = 32; o > 0; o >>= 1) v += __shfl_xor(v, o, 64);
    return v;
}
__device__ __forceinline__ float wave_max(float v) {
    #pragma unroll
    for (int o = 32; o > 0; o >>= 1) v = fmaxf(v, __shfl_xor(v, o, 64));
    return v;
}

// -------- reduce fc1 partials + relu + binary head + fc2 (8 imgs/block) --------
__global__ __launch_bounds__(512) void k_post(const float* __restrict__ part,
                                              const float* __restrict__ fc1b,
                                              const float* __restrict__ fbw,
                                              const float* __restrict__ fbb,
                                              const float* __restrict__ fc2w,
                                              const float* __restrict__ fc2b,
                                              float* __restrict__ out,
                                              float* __restrict__ fc2o)
{
    const int t = threadIdx.x;
    const int im8 = t >> 6;                     // 0..7 == wave id
    const int tl = t & 63;                      // oc
    const int img = blockIdx.x * 8 + im8;
    float s = fc1b[tl];
    #pragma unroll
    for (int ks = 0; ks < 16; ++ks) s += part[((size_t)ks * NIMG + img) * 64 + tl];
    const float f = fmaxf(s, 0.f);
    __shared__ float flc[8][64];
    flc[im8][tl] = f;
    const float bs = wave_sum(f * fbw[tl]);
    if (tl == 0) out[800 + img] = 1.f / (1.f + expf(-(bs + fbb[0])));
    __syncthreads();
    #pragma unroll
    for (int q = 0; q < 2; ++q) {
        const int j = tl + q * 64;
        float a2 = fc2b[j];
        #pragma unroll 8
        for (int k = 0; k < 64; ++k) a2 = fmaf(flc[im8][k], fc2w[j * 64 + k], a2);
        fc2o[(size_t)img * 128 + j] = a2;
    }
}

// ---------------- fusion + softmax + 32-iter water-filling rebalance --------
__global__ __launch_bounds__(64) void k_final(const float* __restrict__ hlast,
                                              const float* __restrict__ fc2o,
                                              const float* __restrict__ gw,
                                              const float* __restrict__ gb,
                                              const float* __restrict__ fw,
                                              const float* __restrict__ fb,
                                              const float* __restrict__ finw,
                                              const float* __restrict__ finb,
                                              float* __restrict__ out)
{
    const int b = blockIdx.x, t = threadIdx.x;
    __shared__ float cf[128], nf[64], fu[64];
    #pragma unroll
    for (int jj = 0; jj < 2; ++jj) {
        const int j = t + jj * 64;
        float s = 0.f;
        for (int n = 0; n < NSTK; ++n) s += fc2o[(size_t)(b * NSTK + n) * 128 + j];
        cf[j] = s * (1.0f / 50.0f);
    }
    float s = 0.f;
    if (t < NSTK) {
        s = gb[t];
        for (int k = 0; k < HID; ++k) s = fmaf(hlast[b * HID + k], gw[t * HID + k], s);
    }
    nf[t] = (t < NSTK) ? s : 0.f;
    __syncthreads();
    float f = fb[t];
    for (int k = 0; k < NSTK; ++k) f = fmaf(nf[k], fw[t * 178 + k], f);
    for (int k = 0; k < 128; ++k) f = fmaf(cf[k], fw[t * 178 + 50 + k], f);
    fu[t] = fmaxf(f, 0.f);
    __syncthreads();
    float L = -3.4e38f;
    if (t < NSTK) {
        L = finb[t];
        for (int k = 0; k < 64; ++k) L = fmaf(fu[k], finw[t * 64 + k], L);
    }
    const float m = wave_max(L);
    const float e = (t < NSTK) ? expf(L - m) : 0.f;
    const float se = wave_sum(e);
    const float wv = e / se;
    float old = wv;
    float wc = fminf(fmaxf(wv, 0.f), 0.1f);
    for (int it = 0; it < 32; ++it) {
        const float leftover = wave_sum(old - wc);
        const bool mask = (wc != 0.1f);
        const float ssum = wave_sum(mask ? wc : 0.f);
        const float gift = (mask && ssum > 0.f) ? leftover * wc / ssum : 0.f;
        old = wc + gift;
        wc = fminf(fmaxf(old, 0.f), 0.1f);
    }
    if (t < NSTK) out[b * NSTK + t] = wc;
}

// ---------------------------------------------------------------------------
extern "C" void kernel_launch(void* const* d_in, const int* in_sizes, int n_in,
                              void* d_out, int out_size, void* d_ws, size_t ws_size,
                              hipStream_t stream)
{
    const float* x_num = (const float*)d_in[0];
    const float* x_img = (const float*)d_in[1];
    const float* c1w  = (const float*)d_in[2];
    const float* c1b  = (const float*)d_in[3];
    const float* c2w  = (const float*)d_in[4];
    const float* c2b  = (const float*)d_in[5];
    const float* fc1w = (const float*)d_in[6];
    const float* fc1b = (const float*)d_in[7];
    const float* fbw  = (const float*)d_in[8];
    const float* fbb  = (const float*)d_in[9];
    const float* fc2w = (const float*)d_in[10];
    const float* fc2b = (const float*)d_in[11];
    const float* wih  = (const float*)d_in[12];
    const float* whh  = (const float*)d_in[13];
    const float* bih  = (const float*)d_in[14];
    const float* bhh  = (const float*)d_in[15];
    const float* gw   = (const float*)d_in[16];
    const float* gb   = (const float*)d_in[17];
    const float* fw   = (const float*)d_in[18];
    const float* fb   = (const float*)d_in[19];
    const float* finw = (const float*)d_in[20];
    const float* finb = (const float*)d_in[21];
    float* out = (float*)d_out;
    float* ws  = (float*)d_ws;
    if (ws_size < (size_t)WS_FLOATS * 4) return;

    ushort_t* whhf  = (ushort_t*)(ws + OFF_WHHF);
    ushort_t* wprep = (ushort_t*)(ws + OFF_WPREP);
    ushort_t* wfc1  = (ushort_t*)(ws + OFF_WFC1);
    float* GI       = ws + OFF_GI;
    float* hlast    = ws + OFF_HLAST;
    ushort_t* pool2 = (ushort_t*)(ws + OFF_POOL2);
    float* fc2o     = ws + OFF_FC2O;
    float* part     = ws + OFF_PART;
    unsigned int* w1h = (unsigned int*)(ws + OFF_W1H);

    (void)hipFuncSetAttribute(reinterpret_cast<const void*>(k_mega),
                              hipFuncAttributeMaxDynamicSharedMemorySize, SMEM_BYTES);

    k_pre   <<<960 + 2737, 384, 0, stream>>>(x_num, wih, bih, whh, c2w, fc1w, c1w, c1b,
                                             GI, whhf, wprep, wfc1, w1h);
    k_mega  <<<2 * NIMG + 1, 512, SMEM_BYTES, stream>>>(x_img, w1h, c2b, wprep,
                                                        GI, whhf, bhh, pool2, hlast);
    k_fc1   <<<50 * 16, 256, 0, stream>>>(pool2, wfc1, part);
    k_post  <<<100, 512, 0, stream>>>(part, fc1b, fbw, fbb, fc2w, fc2b, out, fc2o);
    k_final <<<NBATCH, 64, 0, stream>>>(hlast, fc2o, gw, gb, fw, fb, finw, finb, out);
}

// Round 15
// 142.451 us; speedup vs baseline: 1.3310x; 1.0079x over previous
//
#include <hip/hip_runtime.h>
#include <hip/hip_bf16.h>
#include <hip/hip_fp16.h>

typedef unsigned short ushort_t;
typedef short short8_t __attribute__((ext_vector_type(8)));
typedef _Float16 half8_t __attribute__((ext_vector_type(8)));
typedef _Float16 h2 __attribute__((ext_vector_type(2)));
typedef float f32x4 __attribute__((ext_vector_type(4)));
typedef float f32x16 __attribute__((ext_vector_type(16)));

#define NBATCH 16
#define SEQ    60
#define NSTK   50
#define HID    128
#define G3     384
#define NIMG   800
#define IH     64
#define IW     60
#define P1H    32
#define P1W    30
#define P2C    64
#define FCIN   15360

// ---- workspace layout (float offsets) ----
#define OFF_WHHF   0u          // 49152 ushort  = 24576 f   (GRU W_hh bf16 frags)
#define OFF_WPREP  24576u      // 18432 ushort  = 9216 f    (conv2 W f16 A-frags)
#define OFF_WFC1   33792u      // 983040 ushort = 491520 f  (fc1 W bf16 frags)
#define OFF_GI     525312u     // 368640 f
#define OFF_HLAST  893952u     // 2048 f
#define OFF_POOL2  896000u     // 800*15360 bf16 = 6144000 f
#define OFF_FC2O   7040000u    // 102400 f
#define OFF_PART   7142400u    // 16*800*64 = 819200 f
#define OFF_W1H    7961600u    // 160 uint (144 w1 half2 pairs + 16 c1b half2)
#define WS_FLOATS  7961760u    // ~31.8 MB

// swizzle element counts for k_pre
#define E_WHH  49152
#define E_WPR  18432
#define E_FC1  983040
#define E_W1H  160
#define E_TOT  (E_WHH + E_WPR + E_FC1 + E_W1H)   // 1050784 -> 2737 blocks of 384

// ------------- shared-memory layouts (half-image CNN blocks) -------------
struct __align__(16) ConvS {
    ushort_t pool1t[18][4][32][8];     // 36864 B  f16 bits, [ly][cg][xs][ch8]
    union {
        float    imgp[35][60];         //  8400 B  (conv1 phase)
        ushort_t pool2s[64][120];      // 15360 B  (conv2 staging, bf16)
    } u;
    unsigned int w1s[160];             //   640 B  conv1 f16-pair weights+bias (LDS broadcast)
    float        c2bs[64];             //   256 B  conv2 bias
};                                      // 53120 B
struct __align__(16) GruS {
    ushort_t hb[2][16 * 136];          // 8704 B, double-buffered h (bf16)
};
#define SMEM_BYTES 53120

__device__ __forceinline__ float fast_sig(float x) {
    const float e = __expf(-x);
    return __builtin_amdgcn_rcpf(1.f + e);
}
__device__ __forceinline__ float fast_tanh(float x) {
    const float xc = fmaxf(fminf(x, 15.f), -15.f);
    const float e = __expf(2.f * xc);
    return (e - 1.f) * __builtin_amdgcn_rcpf(e + 1.f);
}
__device__ __forceinline__ h2 hmax2v(h2 a, h2 b) {      // lowers to v_pk_max_f16
    h2 r;
    r[0] = a[0] > b[0] ? a[0] : b[0];
    r[1] = a[1] > b[1] ? a[1] : b[1];
    return r;
}

// ---------------- k_pre: GI (blocks 0..959) + weight swizzles (960..) ----------------
__global__ __launch_bounds__(384) void k_pre(const float* __restrict__ xnum,
                                             const float* __restrict__ wih,
                                             const float* __restrict__ bih,
                                             const float* __restrict__ whh,
                                             const float* __restrict__ c2w,
                                             const float* __restrict__ fc1w,
                                             const float* __restrict__ c1w,
                                             const float* __restrict__ c1b,
                                             float* __restrict__ GI,
                                             ushort_t* __restrict__ whhf,
                                             ushort_t* __restrict__ wprep,
                                             ushort_t* __restrict__ wfc1,
                                             unsigned int* __restrict__ w1h)
{
    const int bid = blockIdx.x;
    if (bid < 960) {
        const int s = bid >> 4, b = bid & 15;
        const int j = threadIdx.x;
        const float* xr = xnum + (size_t)(b * SEQ + s) * NSTK;   // block-uniform -> scalar loads
        const float* wr = wih + (size_t)j * NSTK;
        float a = bih[j];
        #pragma unroll 10
        for (int k = 0; k < NSTK; ++k) a = fmaf(xr[k], wr[k], a);
        GI[((size_t)s * 16 + b) * G3 + j] = a;
        return;
    }
    const int idx = (bid - 960) * 384 + threadIdx.x;
    if (idx < E_WHH) {
        const int e = idx;                  // (((jt*4+ks)*64 + l)*8 + i)  bf16 (GRU)
        const int i = e & 7, l = (e >> 3) & 63, ksj = e >> 9;
        const int ks = ksj & 3, jt = ksj >> 2;
        const int j = jt * 16 + (l & 15);
        const int k = ks * 32 + ((l >> 4) << 3) + i;
        __hip_bfloat16 hv = __float2bfloat16(whh[j * HID + k]);
        whhf[e] = *(ushort_t*)&hv;
    } else if (idx < E_WHH + E_WPR) {
        const int e = idx - E_WHH;          // conv2 A-frags, F16
        const int i = e & 7, l = (e >> 3) & 63, rest = e >> 9;
        const int ks = rest & 1, mt = rest >> 1;
        const int tap = mt % 9, mm = mt / 9;
        const int oc = mm * 32 + (l & 31);
        const int ic = ks * 16 + ((l >> 5) << 3) + i;
        const _Float16 hv = (_Float16)c2w[((size_t)oc * 32 + ic) * 9 + tap];
        wprep[e] = *(const ushort_t*)&hv;
    } else if (idx < E_WHH + E_WPR + E_FC1) {
        const int e = idx - (E_WHH + E_WPR); // fc1 B-frags bf16
        const int i = e & 7, l = (e >> 3) & 63, rest = e >> 9;
        const int n = rest & 3, T = rest >> 2;
        const int oc = n * 16 + (l & 15);
        const int k = T * 32 + ((l >> 4) << 3) + i;
        __hip_bfloat16 hv = __float2bfloat16(fc1w[(size_t)oc * FCIN + k]);
        wfc1[e] = *(ushort_t*)&hv;
    } else if (idx < E_TOT) {
        const int e = idx - (E_WHH + E_WPR + E_FC1);  // conv1 f16-pair weights + bias
        if (e < 144) {
            const int p = e / 9, tap = e - p * 9;     // pair p -> ch (p>>2)*8+(p&3)*2
            const int ch0 = (p >> 2) * 8 + (p & 3) * 2;
            const _Float16 lo = (_Float16)c1w[ch0 * 9 + tap];
            const _Float16 hi = (_Float16)c1w[(ch0 + 1) * 9 + tap];
            w1h[p * 9 + tap] = ((unsigned)*(const ushort_t*)&hi << 16) | *(const ushort_t*)&lo;
        } else {
            const int p = e - 144;
            const int ch0 = (p >> 2) * 8 + (p & 3) * 2;
            const _Float16 lo = (_Float16)c1b[ch0];
            const _Float16 hi = (_Float16)c1b[ch0 + 1];
            w1h[144 + p] = ((unsigned)*(const ushort_t*)&hi << 16) | *(const ushort_t*)&lo;
        }
    }
}

// ------- mega: block 0 = GRU, blocks 1..1600 = one image HALF each -------
__global__ __launch_bounds__(512, 2) void k_mega(const float* __restrict__ x_img,
                                                 const unsigned int* __restrict__ w1h,
                                                 const float* __restrict__ c2b,
                                                 const ushort_t* __restrict__ wprep,
                                                 const float* __restrict__ GI,
                                                 const ushort_t* __restrict__ whhf,
                                                 const float* __restrict__ bhh,
                                                 ushort_t* __restrict__ pool2,
                                                 float* __restrict__ hlast)
{
    extern __shared__ char smraw[];
    const int tid = threadIdx.x;
    const int bid = blockIdx.x;

    if (bid == 0) {
        // ===== GRU: one barrier/step, gates fully in-register =====
        GruS* g = (GruS*)smraw;
        const int w = tid >> 6, l = tid & 63;
        const int arow = l & 15, kq = l >> 4;          // A-frag: row=b index, k-chunk
        const int hh = w * 16 + (l & 15);              // D col -> hh
        const int b0 = (l >> 4) * 4;                   // D rows b0..b0+3
        short8_t wfr[3][4];
        #pragma unroll
        for (int g3 = 0; g3 < 3; ++g3)
            #pragma unroll
            for (int ks = 0; ks < 4; ++ks)
                wfr[g3][ks] = *(const short8_t*)&whhf[((((g3 * 8 + w) * 4 + ks) * 64 + l) * 8)];
        const float bhr = bhh[hh];
        const float bhz = bhh[128 + hh];
        const float bhn = bhh[256 + hh];
        float h[4] = {0.f, 0.f, 0.f, 0.f};
        for (int i = tid; i < 1088; i += 512) ((unsigned int*)g->hb[0])[i] = 0u;
        __syncthreads();

        int cur = 0;
        for (int s = 0; s < SEQ; ++s) {
            const float* gis = GI + ((size_t)s * 16 + b0) * G3 + hh;
            float cr[4], cz[4], cn[4];
            #pragma unroll
            for (int r = 0; r < 4; ++r) {
                cr[r] = gis[r * G3];
                cz[r] = gis[r * G3 + 128];
                cn[r] = gis[r * G3 + 256];
            }
            f32x4 ar = {0.f, 0.f, 0.f, 0.f};
            f32x4 az = {0.f, 0.f, 0.f, 0.f};
            f32x4 an = {0.f, 0.f, 0.f, 0.f};
            #pragma unroll
            for (int ks = 0; ks < 4; ++ks) {
                const short8_t af = *(const short8_t*)&g->hb[cur][arow * 136 + ks * 32 + kq * 8];
                ar = __builtin_amdgcn_mfma_f32_16x16x32_bf16(af, wfr[0][ks], ar, 0, 0, 0);
                az = __builtin_amdgcn_mfma_f32_16x16x32_bf16(af, wfr[1][ks], az, 0, 0, 0);
                an = __builtin_amdgcn_mfma_f32_16x16x32_bf16(af, wfr[2][ks], an, 0, 0, 0);
            }
            const int nxt = cur ^ 1;
            #pragma unroll
            for (int r = 0; r < 4; ++r) {
                const float rg = fast_sig(cr[r] + ar[r] + bhr);
                const float zg = fast_sig(cz[r] + az[r] + bhz);
                const float ng = fast_tanh(cn[r] + rg * (an[r] + bhn));
                h[r] = (1.f - zg) * ng + zg * h[r];
                __hip_bfloat16 t = __float2bfloat16(h[r]);
                g->hb[nxt][(b0 + r) * 136 + hh] = *(ushort_t*)&t;
            }
            __syncthreads();
            cur = nxt;
        }
        #pragma unroll
        for (int r = 0; r < 4; ++r) hlast[(b0 + r) * HID + hh] = h[r];
        return;
    }

    // ================== CNN branch, one image HALF per block ==================
    ConvS* c = (ConvS*)smraw;
    const int img  = (bid - 1) >> 1;
    const int half = (bid - 1) & 1;
    const float* xim = x_img + (size_t)img * (IH * IW);
    const int rowbase = 29 * half;              // first image row in LDS

    // zero halo rows/cols + stage conv weights/biases into LDS
    {
        const short8_t z = {0, 0, 0, 0, 0, 0, 0, 0};
        const int zrow = half ? 17 : 0;
        if (tid < 128) {                        // zrow: 4 cg * 32 xs
            const int cg = tid >> 5, xs = tid & 31;
            *(short8_t*)&c->pool1t[zrow][cg][xs][0] = z;
        } else if (tid < 272) {                 // halo cols: 18 ly * 4 cg * 2
            const int q = tid - 128;
            const int ly = q / 8, cg = (q >> 1) & 3, xs = (q & 1) * 31;
            *(short8_t*)&c->pool1t[ly][cg][xs][0] = z;
        } else if (tid < 432) {                 // conv1 weights+bias to LDS
            c->w1s[tid - 272] = w1h[tid - 272];
        } else if (tid < 496) {                 // conv2 bias to LDS
            c->c2bs[tid - 432] = c2b[tid - 432];
        }
    }
    // copy 35 image rows to LDS (float4: 525 > 512 -> strided loop)
    {
        const f32x4* src = (const f32x4*)(xim + rowbase * IW);
        f32x4* dst = (f32x4*)c->u.imgp;
        for (int i = tid; i < 525; i += 512) dst[i] = src[i];
    }
    __syncthreads();

    // ---- conv1+relu+pool1 (packed f16): 17 pool rows x 30 px = 510 jobs ----
    if (tid < 510) {
        const int gj = tid / 30, px = tid - gj * 30;
        const int g = half * 15 + gj;
        const int ly = gj + 1 - half;
        const h2 z2 = {(_Float16)0.f, (_Float16)0.f};
        h2 patch2[4][4];
        #pragma unroll
        for (int yy = 0; yy < 4; ++yy) {
            const int giy = 2 * g - 1 + yy;
            const int liy = giy - rowbase;
            #pragma unroll
            for (int xx = 0; xx < 4; ++xx) {
                const int ix = 2 * px - 1 + xx;
                const float v = (giy >= 0 && giy < IH && ix >= 0 && ix < IW)
                                    ? c->u.imgp[liy][ix] : 0.f;
                const _Float16 vh = (_Float16)v;
                h2 p2; p2[0] = vh; p2[1] = vh;
                patch2[yy][xx] = p2;
            }
        }
        #pragma unroll
        for (int cg = 0; cg < 4; ++cg) {
            unsigned int ov[4];
            #pragma unroll
            for (int pr = 0; pr < 4; ++pr) {
                const int p = cg * 4 + pr;
                h2 wv[9];
                #pragma unroll
                for (int t = 0; t < 9; ++t) {          // uniform LDS addr -> broadcast
                    const unsigned int wu = c->w1s[p * 9 + t];
                    wv[t] = *(const h2*)&wu;
                }
                h2 a00 = z2, a01 = z2, a10 = z2, a11 = z2;
                #pragma unroll
                for (int ky = 0; ky < 3; ++ky)
                    #pragma unroll
                    for (int kx = 0; kx < 3; ++kx) {
                        const h2 wt = wv[ky * 3 + kx];
                        a00 = wt * patch2[ky][kx]     + a00;   // v_pk_fma_f16
                        a01 = wt * patch2[ky][kx + 1] + a01;
                        a10 = wt * patch2[ky + 1][kx] + a10;
                        a11 = wt * patch2[ky + 1][kx + 1] + a11;
                    }
                const unsigned int bu = c->w1s[144 + p];
                const h2 bia2 = *(const h2*)&bu;
                h2 m = hmax2v(hmax2v(a00, a01), hmax2v(a10, a11));
                h2 r = hmax2v(m + bia2, z2);
                ov[pr] = *(unsigned int*)&r;
            }
            *(uint4*)&c->pool1t[ly][cg][px + 1][0] = *(uint4*)ov;
        }
    }
    __syncthreads();   // conv1 done; imgp dead -> pool2s reuse

    // ---- conv2 f16 MFMA 32x32x16 implicit GEMM, staged flush ----
    {
        const int w  = tid >> 6, l = tid & 63;
        const int m  = w & 1;
        const int hi = l >> 5;
        const int col = l & 31;

        half8_t af[9][2];
        #pragma unroll
        for (int tap = 0; tap < 9; ++tap)
            #pragma unroll
            for (int ks = 0; ks < 2; ++ks)
                af[tap][ks] = *(const half8_t*)&wprep[(((m * 9 + tap) * 2 + ks) * 64 + l) * 8];
        float bia[16];
        #pragma unroll
        for (int r = 0; r < 16; ++r)
            bia[r] = c->c2bs[m * 32 + (r & 3) + 8 * (r >> 2) + 4 * hi];

        const bool wr = ((col & 1) == 0) && (col < 30);
        const int px = col >> 1;

        #pragma unroll
        for (int yy = 0; yy < 2; ++yy) {
            const int ypl = (w >> 1) + yy * 4;           // 0..7 local pooled row
            f32x16 a0, a1;
            #pragma unroll
            for (int r = 0; r < 16; ++r) { a0[r] = 0.f; a1[r] = 0.f; }
            #pragma unroll
            for (int ro = 0; ro < 4; ++ro) {
                const int ly = 2 * ypl + ro;             // 0..17, halo rows pre-zeroed
                half8_t bf[3][2];
                #pragma unroll
                for (int kx = 0; kx < 3; ++kx)
                    #pragma unroll
                    for (int ks = 0; ks < 2; ++ks)
                        bf[kx][ks] = *(const half8_t*)&c->pool1t[ly][ks * 2 + hi][kx + col][0];
                if (ro < 3) {
                    #pragma unroll
                    for (int kx = 0; kx < 3; ++kx)
                        #pragma unroll
                        for (int ks = 0; ks < 2; ++ks)
                            a0 = __builtin_amdgcn_mfma_f32_32x32x16_f16(af[ro * 3 + kx][ks], bf[kx][ks], a0, 0, 0, 0);
                }
                if (ro >= 1) {
                    #pragma unroll
                    for (int kx = 0; kx < 3; ++kx)
                        #pragma unroll
                        for (int ks = 0; ks < 2; ++ks)
                            a1 = __builtin_amdgcn_mfma_f32_32x32x16_f16(af[(ro - 1) * 3 + kx][ks], bf[kx][ks], a1, 0, 0, 0);
                }
            }
            #pragma unroll
            for (int r = 0; r < 16; ++r) {
                float v = fmaxf(a0[r], a1[r]);
                v = fmaxf(v, __shfl_xor(v, 1, 64));
                v = fmaxf(v + bia[r], 0.f);
                if (wr) {
                    const int oc = m * 32 + (r & 3) + 8 * (r >> 2) + 4 * hi;
                    __hip_bfloat16 hv = __float2bfloat16(v);
                    c->u.pool2s[oc][ypl * 15 + px] = *(ushort_t*)&hv;
                }
            }
        }
        __syncthreads();   // staging complete
        // coalesced flush: 960 int4 = 64 oc x 15 int4 (this half's 120 ushorts/oc)
        {
            int4* dst = (int4*)(pool2 + (size_t)img * FCIN);
            const int4* src = (const int4*)c->u.pool2s;
            #pragma unroll
            for (int jj = 0; jj < 2; ++jj) {
                const int i = tid + jj * 512;
                if (i < 960) {
                    const int oc = i / 15, cc = i - oc * 15;
                    dst[oc * 30 + half * 15 + cc] = src[i];
                }
            }
        }
    }
}

// -------- fc1 split-K MFMA: 50 M-tiles x 16 K-splits, part[ks][img][oc] --------
__global__ __launch_bounds__(256) void k_fc1(const ushort_t* __restrict__ pool2,
                                             const ushort_t* __restrict__ wfc1,
                                             float* __restrict__ part)
{
    const int mt = blockIdx.x >> 4;             // 0..49 (16 images)
    const int ks = blockIdx.x & 15;             // K-split of 960
    const int n = threadIdx.x >> 6, l = threadIdx.x & 63;   // wave = oc tile
    const int arow = l & 15, kq = l >> 4;
    const int img16 = mt * 16;
    const ushort_t* Ab = pool2 + (size_t)(img16 + arow) * FCIN + ks * 960 + kq * 8;
    const ushort_t* Bb = wfc1 + ((size_t)(ks * 30 * 4 + n) * 64 + l) * 8;
    f32x4 acc0 = {0.f, 0.f, 0.f, 0.f}, acc1 = {0.f, 0.f, 0.f, 0.f};
    #pragma unroll 10
    for (int t = 0; t < 30; t += 2) {
        const short8_t aA = *(const short8_t*)(Ab + (size_t)t * 32);
        const short8_t bA = *(const short8_t*)(Bb + (size_t)t * 2048);
        const short8_t aB = *(const short8_t*)(Ab + (size_t)(t + 1) * 32);
        const short8_t bB = *(const short8_t*)(Bb + (size_t)(t + 1) * 2048);
        acc0 = __builtin_amdgcn_mfma_f32_16x16x32_bf16(aA, bA, acc0, 0, 0, 0);
        acc1 = __builtin_amdgcn_mfma_f32_16x16x32_bf16(aB, bB, acc1, 0, 0, 0);
    }
    float* dst = &part[((size_t)ks * NIMG + img16 + kq * 4) * 64 + n * 16 + arow];
    #pragma unroll
    for (int r = 0; r < 4; ++r)
        dst[(size_t)r * 64] = acc0[r] + acc1[r];
}

__device__ __forceinline__ float wave_sum(float v) {
    #pragma unroll
    for (int o = 32; o > 0; o >>= 1) v += __shfl_xor(v, o, 64);
    return v;
}
__device__ __forceinline__ float wave_max(float v) {
    #pragma unroll
    for (int o = 32; o > 0; o >>= 1) v = fmaxf(v, __shfl_xor(v, o, 64));
    return v;
}

// -------- reduce fc1 partials + relu + binary head + fc2 (8 imgs/block) --------
__global__ __launch_bounds__(512) void k_post(const float* __restrict__ part,
                                              const float* __restrict__ fc1b,
                                              const float* __restrict__ fbw,
                                              const float* __restrict__ fbb,
                                              const float* __restrict__ fc2w,
                                              const float* __restrict__ fc2b,
                                              float* __restrict__ out,
                                              float* __restrict__ fc2o)
{
    const int t = threadIdx.x;
    const int im8 = t >> 6;                     // 0..7 == wave id
    const int tl = t & 63;                      // oc
    const int img = blockIdx.x * 8 + im8;
    float s = fc1b[tl];
    #pragma unroll
    for (int ks = 0; ks < 16; ++ks) s += part[((size_t)ks * NIMG + img) * 64 + tl];
    const float f = fmaxf(s, 0.f);
    __shared__ float flc[8][64];
    flc[im8][tl] = f;
    const float bs = wave_sum(f * fbw[tl]);
    if (tl == 0) out[800 + img] = 1.f / (1.f + expf(-(bs + fbb[0])));
    __syncthreads();
    #pragma unroll
    for (int q = 0; q < 2; ++q) {
        const int j = tl + q * 64;
        float a2 = fc2b[j];
        #pragma unroll 8
        for (int k = 0; k < 64; ++k) a2 = fmaf(flc[im8][k], fc2w[j * 64 + k], a2);
        fc2o[(size_t)img * 128 + j] = a2;
    }
}

// ---------------- fusion + softmax + 32-iter water-filling rebalance --------
__global__ __launch_bounds__(64) void k_final(const float* __restrict__ hlast,
                                              const float* __restrict__ fc2o,
                                              const float* __restrict__ gw,
                                              const float* __restrict__ gb,
                                              const float* __restrict__ fw,
                                              const float* __restrict__ fb,
                                              const float* __restrict__ finw,
                                              const float* __restrict__ finb,
                                              float* __restrict__ out)
{
    const int b = blockIdx.x, t = threadIdx.x;
    __shared__ float cf[128], nf[64], fu[64];
    #pragma unroll
    for (int jj = 0; jj < 2; ++jj) {
        const int j = t + jj * 64;
        float s = 0.f;
        for (int n = 0; n < NSTK; ++n) s += fc2o[(size_t)(b * NSTK + n) * 128 + j];
        cf[j] = s * (1.0f / 50.0f);
    }
    float s = 0.f;
    if (t < NSTK) {
        s = gb[t];
        for (int k = 0; k < HID; ++k) s = fmaf(hlast[b * HID + k], gw[t * HID + k], s);
    }
    nf[t] = (t < NSTK) ? s : 0.f;
    __syncthreads();
    float f = fb[t];
    for (int k = 0; k < NSTK; ++k) f = fmaf(nf[k], fw[t * 178 + k], f);
    for (int k = 0; k < 128; ++k) f = fmaf(cf[k], fw[t * 178 + 50 + k], f);
    fu[t] = fmaxf(f, 0.f);
    __syncthreads();
    float L = -3.4e38f;
    if (t < NSTK) {
        L = finb[t];
        for (int k = 0; k < 64; ++k) L = fmaf(fu[k], finw[t * 64 + k], L);
    }
    const float m = wave_max(L);
    const float e = (t < NSTK) ? expf(L - m) : 0.f;
    const float se = wave_sum(e);
    const float wv = e / se;
    float old = wv;
    float wc = fminf(fmaxf(wv, 0.f), 0.1f);
    for (int it = 0; it < 32; ++it) {
        const float leftover = wave_sum(old - wc);
        const bool mask = (wc != 0.1f);
        const float ssum = wave_sum(mask ? wc : 0.f);
        const float gift = (mask && ssum > 0.f) ? leftover * wc / ssum : 0.f;
        old = wc + gift;
        wc = fminf(fmaxf(old, 0.f), 0.1f);
    }
    if (t < NSTK) out[b * NSTK + t] = wc;
}

// ---------------------------------------------------------------------------
extern "C" void kernel_launch(void* const* d_in, const int* in_sizes, int n_in,
                              void* d_out, int out_size, void* d_ws, size_t ws_size,
                              hipStream_t stream)
{
    const float* x_num = (const float*)d_in[0];
    const float* x_img = (const float*)d_in[1];
    const float* c1w  = (const float*)d_in[2];
    const float* c1b  = (const float*)d_in[3];
    const float* c2w  = (const float*)d_in[4];
    const float* c2b  = (const float*)d_in[5];
    const float* fc1w = (const float*)d_in[6];
    const float* fc1b = (const float*)d_in[7];
    const float* fbw  = (const float*)d_in[8];
    const float* fbb  = (const float*)d_in[9];
    const float* fc2w = (const float*)d_in[10];
    const float* fc2b = (const float*)d_in[11];
    const float* wih  = (const float*)d_in[12];
    const float* whh  = (const float*)d_in[13];
    const float* bih  = (const float*)d_in[14];
    const float* bhh  = (const float*)d_in[15];
    const float* gw   = (const float*)d_in[16];
    const float* gb   = (const float*)d_in[17];
    const float* fw   = (const float*)d_in[18];
    const float* fb   = (const float*)d_in[19];
    const float* finw = (const float*)d_in[20];
    const float* finb = (const float*)d_in[21];
    float* out = (float*)d_out;
    float* ws  = (float*)d_ws;
    if (ws_size < (size_t)WS_FLOATS * 4) return;

    ushort_t* whhf  = (ushort_t*)(ws + OFF_WHHF);
    ushort_t* wprep = (ushort_t*)(ws + OFF_WPREP);
    ushort_t* wfc1  = (ushort_t*)(ws + OFF_WFC1);
    float* GI       = ws + OFF_GI;
    float* hlast    = ws + OFF_HLAST;
    ushort_t* pool2 = (ushort_t*)(ws + OFF_POOL2);
    float* fc2o     = ws + OFF_FC2O;
    float* part     = ws + OFF_PART;
    unsigned int* w1h = (unsigned int*)(ws + OFF_W1H);

    (void)hipFuncSetAttribute(reinterpret_cast<const void*>(k_mega),
                              hipFuncAttributeMaxDynamicSharedMemorySize, SMEM_BYTES);

    k_pre   <<<960 + 2737, 384, 0, stream>>>(x_num, wih, bih, whh, c2w, fc1w, c1w, c1b,
                                             GI, whhf, wprep, wfc1, w1h);
    k_mega  <<<2 * NIMG + 1, 512, SMEM_BYTES, stream>>>(x_img, w1h, c2b, wprep,
                                                        GI, whhf, bhh, pool2, hlast);
    k_fc1   <<<50 * 16, 256, 0, stream>>>(pool2, wfc1, part);
    k_post  <<<100, 512, 0, stream>>>(part, fc1b, fbw, fbb, fc2w, fc2b, out, fc2o);
    k_final <<<NBATCH, 64, 0, stream>>>(hlast, fc2o, gw, gb, fw, fb, finw, finb, out);
}

// Round 16
// 137.553 us; speedup vs baseline: 1.3784x; 1.0356x over previous
//
#include <hip/hip_runtime.h>
#include <hip/hip_bf16.h>
#include <hip/hip_fp16.h>

typedef unsigned short ushort_t;
typedef short short8_t __attribute__((ext_vector_type(8)));
typedef _Float16 half8_t __attribute__((ext_vector_type(8)));
typedef _Float16 h2 __attribute__((ext_vector_type(2)));
typedef float f32x4 __attribute__((ext_vector_type(4)));
typedef float f32x16 __attribute__((ext_vector_type(16)));

#define NBATCH 16
#define SEQ    60
#define NSTK   50
#define HID    128
#define G3     384
#define NIMG   800
#define IH     64
#define IW     60
#define P1H    32
#define P1W    30
#define P2C    64
#define FCIN   15360

// ---- workspace layout (float offsets) ----
#define OFF_WHHF   0u          // 49152 ushort  = 24576 f   (GRU W_hh bf16 frags)
#define OFF_WPREP  24576u      // 18432 ushort  = 9216 f    (conv2 W f16 A-frags)
#define OFF_WFC1   33792u      // 983040 ushort = 491520 f  (fc1 W bf16 frags)
#define OFF_GI     525312u     // 368640 f
#define OFF_HLAST  893952u     // 2048 f
#define OFF_POOL2  896000u     // 800*15360 bf16 = 6144000 f
#define OFF_FC2O   7040000u    // 102400 f
#define OFF_PART   7142400u    // 16*800*64 = 819200 f
#define OFF_W1H    7961600u    // 160 uint
#define OFF_FC2WT  7961760u    // 8192 f (fc2w transposed k-major)
#define WS_FLOATS  7969952u    // ~31.9 MB

// swizzle element counts for k_pre
#define E_WHH  49152
#define E_WPR  18432
#define E_FC1  983040
#define E_W1H  160
#define E_FT   8192
#define E_TOT  (E_WHH + E_WPR + E_FC1 + E_W1H + E_FT)   // 1058976 -> 2758 blocks of 384

// ------------- shared-memory layouts (half-image CNN blocks) -------------
struct __align__(16) ConvS {
    ushort_t pool1t[18][4][32][8];     // 36864 B  f16 bits, [ly][cg][xs][ch8]
    union {
        float    imgp[35][60];         //  8400 B  (conv1 phase)
        ushort_t pool2s[64][120];      // 15360 B  (conv2 staging, bf16)
    } u;
};                                      // 52224 B
struct __align__(16) GruS {
    ushort_t hb[2][16 * 136];          // 8704 B, double-buffered h (bf16)
};
#define SMEM_BYTES 52224

__device__ __forceinline__ float fast_sig(float x) {
    const float e = __expf(-x);
    return __builtin_amdgcn_rcpf(1.f + e);
}
__device__ __forceinline__ float fast_tanh(float x) {
    const float xc = fmaxf(fminf(x, 15.f), -15.f);
    const float e = __expf(2.f * xc);
    return (e - 1.f) * __builtin_amdgcn_rcpf(e + 1.f);
}
__device__ __forceinline__ h2 hmax2v(h2 a, h2 b) {      // lowers to v_pk_max_f16
    h2 r;
    r[0] = a[0] > b[0] ? a[0] : b[0];
    r[1] = a[1] > b[1] ? a[1] : b[1];
    return r;
}

// ---------------- k_pre: GI (blocks 0..959) + weight swizzles (960..) ----------------
__global__ __launch_bounds__(384) void k_pre(const float* __restrict__ xnum,
                                             const float* __restrict__ wih,
                                             const float* __restrict__ bih,
                                             const float* __restrict__ whh,
                                             const float* __restrict__ c2w,
                                             const float* __restrict__ fc1w,
                                             const float* __restrict__ c1w,
                                             const float* __restrict__ c1b,
                                             const float* __restrict__ fc2w,
                                             float* __restrict__ GI,
                                             ushort_t* __restrict__ whhf,
                                             ushort_t* __restrict__ wprep,
                                             ushort_t* __restrict__ wfc1,
                                             unsigned int* __restrict__ w1h,
                                             float* __restrict__ fc2wT)
{
    const int bid = blockIdx.x;
    if (bid < 960) {
        const int s = bid >> 4, b = bid & 15;
        const int j = threadIdx.x;
        const float* xr = xnum + (size_t)(b * SEQ + s) * NSTK;   // block-uniform -> scalar loads
        const float* wr = wih + (size_t)j * NSTK;
        float a = bih[j];
        #pragma unroll 10
        for (int k = 0; k < NSTK; ++k) a = fmaf(xr[k], wr[k], a);
        GI[((size_t)s * 16 + b) * G3 + j] = a;
        return;
    }
    const int idx = (bid - 960) * 384 + threadIdx.x;
    if (idx < E_WHH) {
        const int e = idx;                  // (((jt*4+ks)*64 + l)*8 + i)  bf16 (GRU)
        const int i = e & 7, l = (e >> 3) & 63, ksj = e >> 9;
        const int ks = ksj & 3, jt = ksj >> 2;
        const int j = jt * 16 + (l & 15);
        const int k = ks * 32 + ((l >> 4) << 3) + i;
        __hip_bfloat16 hv = __float2bfloat16(whh[j * HID + k]);
        whhf[e] = *(ushort_t*)&hv;
    } else if (idx < E_WHH + E_WPR) {
        const int e = idx - E_WHH;          // conv2 A-frags, F16
        const int i = e & 7, l = (e >> 3) & 63, rest = e >> 9;
        const int ks = rest & 1, mt = rest >> 1;
        const int tap = mt % 9, mm = mt / 9;
        const int oc = mm * 32 + (l & 31);
        const int ic = ks * 16 + ((l >> 5) << 3) + i;
        const _Float16 hv = (_Float16)c2w[((size_t)oc * 32 + ic) * 9 + tap];
        wprep[e] = *(const ushort_t*)&hv;
    } else if (idx < E_WHH + E_WPR + E_FC1) {
        const int e = idx - (E_WHH + E_WPR); // fc1 B-frags bf16
        const int i = e & 7, l = (e >> 3) & 63, rest = e >> 9;
        const int n = rest & 3, T = rest >> 2;
        const int oc = n * 16 + (l & 15);
        const int k = T * 32 + ((l >> 4) << 3) + i;
        __hip_bfloat16 hv = __float2bfloat16(fc1w[(size_t)oc * FCIN + k]);
        wfc1[e] = *(ushort_t*)&hv;
    } else if (idx < E_WHH + E_WPR + E_FC1 + E_W1H) {
        const int e = idx - (E_WHH + E_WPR + E_FC1);  // conv1 f16-pair weights + bias
        if (e < 144) {
            const int p = e / 9, tap = e - p * 9;     // pair p -> ch (p>>2)*8+(p&3)*2
            const int ch0 = (p >> 2) * 8 + (p & 3) * 2;
            const _Float16 lo = (_Float16)c1w[ch0 * 9 + tap];
            const _Float16 hi = (_Float16)c1w[(ch0 + 1) * 9 + tap];
            w1h[p * 9 + tap] = ((unsigned)*(const ushort_t*)&hi << 16) | *(const ushort_t*)&lo;
        } else {
            const int p = e - 144;
            const int ch0 = (p >> 2) * 8 + (p & 3) * 2;
            const _Float16 lo = (_Float16)c1b[ch0];
            const _Float16 hi = (_Float16)c1b[ch0 + 1];
            w1h[144 + p] = ((unsigned)*(const ushort_t*)&hi << 16) | *(const ushort_t*)&lo;
        }
    } else if (idx < E_TOT) {
        const int e = idx - (E_WHH + E_WPR + E_FC1 + E_W1H);  // fc2wT[k*128+j] = fc2w[j*64+k]
        const int j = e & 127, k = e >> 7;
        fc2wT[e] = fc2w[j * 64 + k];
    }
}

// ------- mega: block 0 = GRU, blocks 1..1600 = one image HALF each (R11 form) -------
__global__ __launch_bounds__(512, 2) void k_mega(const float* __restrict__ x_img,
                                                 const unsigned int* __restrict__ w1h,
                                                 const float* __restrict__ c2b,
                                                 const ushort_t* __restrict__ wprep,
                                                 const float* __restrict__ GI,
                                                 const ushort_t* __restrict__ whhf,
                                                 const float* __restrict__ bhh,
                                                 ushort_t* __restrict__ pool2,
                                                 float* __restrict__ hlast)
{
    extern __shared__ char smraw[];
    const int tid = threadIdx.x;
    const int bid = blockIdx.x;

    if (bid == 0) {
        // ===== GRU: one barrier/step, gates fully in-register =====
        GruS* g = (GruS*)smraw;
        const int w = tid >> 6, l = tid & 63;
        const int arow = l & 15, kq = l >> 4;          // A-frag: row=b index, k-chunk
        const int hh = w * 16 + (l & 15);              // D col -> hh
        const int b0 = (l >> 4) * 4;                   // D rows b0..b0+3
        short8_t wfr[3][4];
        #pragma unroll
        for (int g3 = 0; g3 < 3; ++g3)
            #pragma unroll
            for (int ks = 0; ks < 4; ++ks)
                wfr[g3][ks] = *(const short8_t*)&whhf[((((g3 * 8 + w) * 4 + ks) * 64 + l) * 8)];
        const float bhr = bhh[hh];
        const float bhz = bhh[128 + hh];
        const float bhn = bhh[256 + hh];
        float h[4] = {0.f, 0.f, 0.f, 0.f};
        for (int i = tid; i < 1088; i += 512) ((unsigned int*)g->hb[0])[i] = 0u;
        __syncthreads();

        int cur = 0;
        for (int s = 0; s < SEQ; ++s) {
            const float* gis = GI + ((size_t)s * 16 + b0) * G3 + hh;
            float cr[4], cz[4], cn[4];
            #pragma unroll
            for (int r = 0; r < 4; ++r) {
                cr[r] = gis[r * G3];
                cz[r] = gis[r * G3 + 128];
                cn[r] = gis[r * G3 + 256];
            }
            f32x4 ar = {0.f, 0.f, 0.f, 0.f};
            f32x4 az = {0.f, 0.f, 0.f, 0.f};
            f32x4 an = {0.f, 0.f, 0.f, 0.f};
            #pragma unroll
            for (int ks = 0; ks < 4; ++ks) {
                const short8_t af = *(const short8_t*)&g->hb[cur][arow * 136 + ks * 32 + kq * 8];
                ar = __builtin_amdgcn_mfma_f32_16x16x32_bf16(af, wfr[0][ks], ar, 0, 0, 0);
                az = __builtin_amdgcn_mfma_f32_16x16x32_bf16(af, wfr[1][ks], az, 0, 0, 0);
                an = __builtin_amdgcn_mfma_f32_16x16x32_bf16(af, wfr[2][ks], an, 0, 0, 0);
            }
            const int nxt = cur ^ 1;
            #pragma unroll
            for (int r = 0; r < 4; ++r) {
                const float rg = fast_sig(cr[r] + ar[r] + bhr);
                const float zg = fast_sig(cz[r] + az[r] + bhz);
                const float ng = fast_tanh(cn[r] + rg * (an[r] + bhn));
                h[r] = (1.f - zg) * ng + zg * h[r];
                __hip_bfloat16 t = __float2bfloat16(h[r]);
                g->hb[nxt][(b0 + r) * 136 + hh] = *(ushort_t*)&t;
            }
            __syncthreads();
            cur = nxt;
        }
        #pragma unroll
        for (int r = 0; r < 4; ++r) hlast[(b0 + r) * HID + hh] = h[r];
        return;
    }

    // ================== CNN branch, one image HALF per block ==================
    ConvS* c = (ConvS*)smraw;
    const int img  = (bid - 1) >> 1;
    const int half = (bid - 1) & 1;
    const float* xim = x_img + (size_t)img * (IH * IW);
    const int rowbase = 29 * half;              // first image row in LDS

    // zero unwritten halo row (ly: half0->0, half1->17) + x halo cols 0,31
    {
        const short8_t z = {0, 0, 0, 0, 0, 0, 0, 0};
        const int zrow = half ? 17 : 0;
        if (tid < 128) {
            const int cg = tid >> 5, xs = tid & 31;
            *(short8_t*)&c->pool1t[zrow][cg][xs][0] = z;
        } else if (tid < 272) {
            const int q = tid - 128;
            const int ly = q / 8, cg = (q >> 1) & 3, xs = (q & 1) * 31;
            *(short8_t*)&c->pool1t[ly][cg][xs][0] = z;
        }
    }
    // copy 35 image rows to LDS (float4: 525 > 512 -> strided loop)
    {
        const f32x4* src = (const f32x4*)(xim + rowbase * IW);
        f32x4* dst = (f32x4*)c->u.imgp;
        for (int i = tid; i < 525; i += 512) dst[i] = src[i];
    }
    __syncthreads();

    // ---- conv1+relu+pool1 (packed f16): 17 pool rows x 30 px = 510 jobs ----
    if (tid < 510) {
        const int gj = tid / 30, px = tid - gj * 30;
        const int g = half * 15 + gj;
        const int ly = gj + 1 - half;
        const h2 z2 = {(_Float16)0.f, (_Float16)0.f};
        h2 patch2[4][4];
        #pragma unroll
        for (int yy = 0; yy < 4; ++yy) {
            const int giy = 2 * g - 1 + yy;
            const int liy = giy - rowbase;
            #pragma unroll
            for (int xx = 0; xx < 4; ++xx) {
                const int ix = 2 * px - 1 + xx;
                const float v = (giy >= 0 && giy < IH && ix >= 0 && ix < IW)
                                    ? c->u.imgp[liy][ix] : 0.f;
                const _Float16 vh = (_Float16)v;
                h2 p2; p2[0] = vh; p2[1] = vh;
                patch2[yy][xx] = p2;
            }
        }
        #pragma unroll
        for (int cg = 0; cg < 4; ++cg) {
            unsigned int ov[4];
            #pragma unroll
            for (int pr = 0; pr < 4; ++pr) {
                const int p = cg * 4 + pr;
                h2 wv[9];
                #pragma unroll
                for (int t = 0; t < 9; ++t) {          // uniform -> scalar loads
                    const unsigned int wu = w1h[p * 9 + t];
                    wv[t] = *(const h2*)&wu;
                }
                h2 a00 = z2, a01 = z2, a10 = z2, a11 = z2;
                #pragma unroll
                for (int ky = 0; ky < 3; ++ky)
                    #pragma unroll
                    for (int kx = 0; kx < 3; ++kx) {
                        const h2 wt = wv[ky * 3 + kx];
                        a00 = wt * patch2[ky][kx]     + a00;   // v_pk_fma_f16
                        a01 = wt * patch2[ky][kx + 1] + a01;
                        a10 = wt * patch2[ky + 1][kx] + a10;
                        a11 = wt * patch2[ky + 1][kx + 1] + a11;
                    }
                const unsigned int bu = w1h[144 + p];
                const h2 bia2 = *(const h2*)&bu;
                h2 m = hmax2v(hmax2v(a00, a01), hmax2v(a10, a11));
                h2 r = hmax2v(m + bia2, z2);
                ov[pr] = *(unsigned int*)&r;
            }
            *(uint4*)&c->pool1t[ly][cg][px + 1][0] = *(uint4*)ov;
        }
    }
    __syncthreads();   // conv1 done; imgp dead -> pool2s reuse

    // ---- conv2 f16 MFMA 32x32x16 implicit GEMM, staged flush ----
    {
        const int w  = tid >> 6, l = tid & 63;
        const int m  = w & 1;
        const int hi = l >> 5;
        const int col = l & 31;

        half8_t af[9][2];
        #pragma unroll
        for (int tap = 0; tap < 9; ++tap)
            #pragma unroll
            for (int ks = 0; ks < 2; ++ks)
                af[tap][ks] = *(const half8_t*)&wprep[(((m * 9 + tap) * 2 + ks) * 64 + l) * 8];
        float bia[16];
        #pragma unroll
        for (int r = 0; r < 16; ++r)
            bia[r] = c2b[m * 32 + (r & 3) + 8 * (r >> 2) + 4 * hi];

        const bool wr = ((col & 1) == 0) && (col < 30);
        const int px = col >> 1;

        #pragma unroll
        for (int yy = 0; yy < 2; ++yy) {
            const int ypl = (w >> 1) + yy * 4;           // 0..7 local pooled row
            f32x16 a0, a1;
            #pragma unroll
            for (int r = 0; r < 16; ++r) { a0[r] = 0.f; a1[r] = 0.f; }
            #pragma unroll
            for (int ro = 0; ro < 4; ++ro) {
                const int ly = 2 * ypl + ro;             // 0..17, halo rows pre-zeroed
                half8_t bf[3][2];
                #pragma unroll
                for (int kx = 0; kx < 3; ++kx)
                    #pragma unroll
                    for (int ks = 0; ks < 2; ++ks)
                        bf[kx][ks] = *(const half8_t*)&c->pool1t[ly][ks * 2 + hi][kx + col][0];
                if (ro < 3) {
                    #pragma unroll
                    for (int kx = 0; kx < 3; ++kx)
                        #pragma unroll
                        for (int ks = 0; ks < 2; ++ks)
                            a0 = __builtin_amdgcn_mfma_f32_32x32x16_f16(af[ro * 3 + kx][ks], bf[kx][ks], a0, 0, 0, 0);
                }
                if (ro >= 1) {
                    #pragma unroll
                    for (int kx = 0; kx < 3; ++kx)
                        #pragma unroll
                        for (int ks = 0; ks < 2; ++ks)
                            a1 = __builtin_amdgcn_mfma_f32_32x32x16_f16(af[(ro - 1) * 3 + kx][ks], bf[kx][ks], a1, 0, 0, 0);
                }
            }
            #pragma unroll
            for (int r = 0; r < 16; ++r) {
                float v = fmaxf(a0[r], a1[r]);
                v = fmaxf(v, __shfl_xor(v, 1, 64));
                v = fmaxf(v + bia[r], 0.f);
                if (wr) {
                    const int oc = m * 32 + (r & 3) + 8 * (r >> 2) + 4 * hi;
                    __hip_bfloat16 hv = __float2bfloat16(v);
                    c->u.pool2s[oc][ypl * 15 + px] = *(ushort_t*)&hv;
                }
            }
        }
        __syncthreads();   // staging complete
        // coalesced flush: 960 int4 = 64 oc x 15 int4 (this half's 120 ushorts/oc)
        {
            int4* dst = (int4*)(pool2 + (size_t)img * FCIN);
            const int4* src = (const int4*)c->u.pool2s;
            #pragma unroll
            for (int jj = 0; jj < 2; ++jj) {
                const int i = tid + jj * 512;
                if (i < 960) {
                    const int oc = i / 15, cc = i - oc * 15;
                    dst[oc * 30 + half * 15 + cc] = src[i];
                }
            }
        }
    }
}

// -------- fc1 split-K MFMA: 50 M-tiles x 16 K-splits, part[ks][img][oc] --------
__global__ __launch_bounds__(256) void k_fc1(const ushort_t* __restrict__ pool2,
                                             const ushort_t* __restrict__ wfc1,
                                             float* __restrict__ part)
{
    const int mt = blockIdx.x >> 4;             // 0..49 (16 images)
    const int ks = blockIdx.x & 15;             // K-split of 960
    const int n = threadIdx.x >> 6, l = threadIdx.x & 63;   // wave = oc tile
    const int arow = l & 15, kq = l >> 4;
    const int img16 = mt * 16;
    const ushort_t* Ab = pool2 + (size_t)(img16 + arow) * FCIN + ks * 960 + kq * 8;
    const ushort_t* Bb = wfc1 + ((size_t)(ks * 30 * 4 + n) * 64 + l) * 8;
    f32x4 acc0 = {0.f, 0.f, 0.f, 0.f}, acc1 = {0.f, 0.f, 0.f, 0.f};
    #pragma unroll 10
    for (int t = 0; t < 30; t += 2) {
        const short8_t aA = *(const short8_t*)(Ab + (size_t)t * 32);
        const short8_t bA = *(const short8_t*)(Bb + (size_t)t * 2048);
        const short8_t aB = *(const short8_t*)(Ab + (size_t)(t + 1) * 32);
        const short8_t bB = *(const short8_t*)(Bb + (size_t)(t + 1) * 2048);
        acc0 = __builtin_amdgcn_mfma_f32_16x16x32_bf16(aA, bA, acc0, 0, 0, 0);
        acc1 = __builtin_amdgcn_mfma_f32_16x16x32_bf16(aB, bB, acc1, 0, 0, 0);
    }
    float* dst = &part[((size_t)ks * NIMG + img16 + kq * 4) * 64 + n * 16 + arow];
    #pragma unroll
    for (int r = 0; r < 4; ++r)
        dst[(size_t)r * 64] = acc0[r] + acc1[r];
}

__device__ __forceinline__ float wave_sum(float v) {
    #pragma unroll
    for (int o = 32; o > 0; o >>= 1) v += __shfl_xor(v, o, 64);
    return v;
}
__device__ __forceinline__ float wave_max(float v) {
    #pragma unroll
    for (int o = 32; o > 0; o >>= 1) v = fmaxf(v, __shfl_xor(v, o, 64));
    return v;
}

// -------- k_post: one image per block (800 blocks), coalesced fc2wT --------
__global__ __launch_bounds__(64) void k_post(const float* __restrict__ part,
                                             const float* __restrict__ fc1b,
                                             const float* __restrict__ fbw,
                                             const float* __restrict__ fbb,
                                             const float* __restrict__ fc2wT,
                                             const float* __restrict__ fc2b,
                                             float* __restrict__ out,
                                             float* __restrict__ fc2o)
{
    const int img = blockIdx.x, t = threadIdx.x;
    float s = fc1b[t];
    #pragma unroll
    for (int ks = 0; ks < 16; ++ks) s += part[((size_t)ks * NIMG + img) * 64 + t];
    const float f = fmaxf(s, 0.f);
    __shared__ float fl[64];
    fl[t] = f;
    const float bs = wave_sum(f * fbw[t]);
    if (t == 0) out[800 + img] = 1.f / (1.f + expf(-(bs + fbb[0])));
    __syncthreads();
    float a0 = fc2b[t], a1 = fc2b[t + 64];
    #pragma unroll 8
    for (int k = 0; k < 64; ++k) {
        const float fk = fl[k];
        a0 = fmaf(fk, fc2wT[k * 128 + t], a0);
        a1 = fmaf(fk, fc2wT[k * 128 + 64 + t], a1);
    }
    fc2o[(size_t)img * 128 + t] = a0;
    fc2o[(size_t)img * 128 + 64 + t] = a1;
}

// ---- k_final (256 thr): fusion + softmax + 32-iter water-filling rebalance ----
__global__ __launch_bounds__(256) void k_final(const float* __restrict__ hlast,
                                               const float* __restrict__ fc2o,
                                               const float* __restrict__ gw,
                                               const float* __restrict__ gb,
                                               const float* __restrict__ fw,
                                               const float* __restrict__ fb,
                                               const float* __restrict__ finw,
                                               const float* __restrict__ finb,
                                               float* __restrict__ out)
{
    const int b = blockIdx.x, t = threadIdx.x;
    __shared__ float cfp[2][128], nf[64], fu[64], hl[128];
    // stage hlast row + cf partial sums (2 halves x 25 images each)
    if (t < 128) hl[t] = hlast[b * HID + t];
    {
        const int j = t & 127, hf = t >> 7;
        const float* base = fc2o + ((size_t)(b * NSTK + hf * 25) * 128) + j;
        float s = 0.f;
        #pragma unroll 5
        for (int n = 0; n < 25; ++n) s += base[(size_t)n * 128];
        cfp[hf][j] = s;
    }
    __syncthreads();
    // numerical features (GRU head), wave 0 only
    if (t < 64) {
        float s = 0.f;
        if (t < NSTK) {
            s = gb[t];
            #pragma unroll 8
            for (int k = 0; k < HID; ++k) s = fmaf(hl[k], gw[t * HID + k], s);
        }
        nf[t] = (t < NSTK) ? s : 0.f;
    }
    __syncthreads();
    // fusion + relu, wave 0
    if (t < 64) {
        float f = fb[t];
        #pragma unroll 10
        for (int k = 0; k < NSTK; ++k) f = fmaf(nf[k], fw[t * 178 + k], f);
        #pragma unroll 8
        for (int k = 0; k < 128; ++k) {
            const float cfk = (cfp[0][k] + cfp[1][k]) * (1.0f / 50.0f);
            f = fmaf(cfk, fw[t * 178 + 50 + k], f);
        }
        fu[t] = fmaxf(f, 0.f);
    }
    __syncthreads();
    if (t < 64) {
        float L = -3.4e38f;
        if (t < NSTK) {
            L = finb[t];
            #pragma unroll 8
            for (int k = 0; k < 64; ++k) L = fmaf(fu[k], finw[t * 64 + k], L);
        }
        const float m = wave_max(L);
        const float e = (t < NSTK) ? expf(L - m) : 0.f;
        const float se = wave_sum(e);
        const float wv = e / se;
        float old = wv;
        float wc = fminf(fmaxf(wv, 0.f), 0.1f);
        for (int it = 0; it < 32; ++it) {
            const float leftover = wave_sum(old - wc);
            const bool mask = (wc != 0.1f);
            const float ssum = wave_sum(mask ? wc : 0.f);
            const float gift = (mask && ssum > 0.f) ? leftover * wc / ssum : 0.f;
            old = wc + gift;
            wc = fminf(fmaxf(old, 0.f), 0.1f);
        }
        if (t < NSTK) out[b * NSTK + t] = wc;
    }
}

// ---------------------------------------------------------------------------
extern "C" void kernel_launch(void* const* d_in, const int* in_sizes, int n_in,
                              void* d_out, int out_size, void* d_ws, size_t ws_size,
                              hipStream_t stream)
{
    const float* x_num = (const float*)d_in[0];
    const float* x_img = (const float*)d_in[1];
    const float* c1w  = (const float*)d_in[2];
    const float* c1b  = (const float*)d_in[3];
    const float* c2w  = (const float*)d_in[4];
    const float* c2b  = (const float*)d_in[5];
    const float* fc1w = (const float*)d_in[6];
    const float* fc1b = (const float*)d_in[7];
    const float* fbw  = (const float*)d_in[8];
    const float* fbb  = (const float*)d_in[9];
    const float* fc2w = (const float*)d_in[10];
    const float* fc2b = (const float*)d_in[11];
    const float* wih  = (const float*)d_in[12];
    const float* whh  = (const float*)d_in[13];
    const float* bih  = (const float*)d_in[14];
    const float* bhh  = (const float*)d_in[15];
    const float* gw   = (const float*)d_in[16];
    const float* gb   = (const float*)d_in[17];
    const float* fw   = (const float*)d_in[18];
    const float* fb   = (const float*)d_in[19];
    const float* finw = (const float*)d_in[20];
    const float* finb = (const float*)d_in[21];
    float* out = (float*)d_out;
    float* ws  = (float*)d_ws;
    if (ws_size < (size_t)WS_FLOATS * 4) return;

    ushort_t* whhf  = (ushort_t*)(ws + OFF_WHHF);
    ushort_t* wprep = (ushort_t*)(ws + OFF_WPREP);
    ushort_t* wfc1  = (ushort_t*)(ws + OFF_WFC1);
    float* GI       = ws + OFF_GI;
    float* hlast    = ws + OFF_HLAST;
    ushort_t* pool2 = (ushort_t*)(ws + OFF_POOL2);
    float* fc2o     = ws + OFF_FC2O;
    float* part     = ws + OFF_PART;
    unsigned int* w1h = (unsigned int*)(ws + OFF_W1H);
    float* fc2wT    = ws + OFF_FC2WT;

    (void)hipFuncSetAttribute(reinterpret_cast<const void*>(k_mega),
                              hipFuncAttributeMaxDynamicSharedMemorySize, SMEM_BYTES);

    k_pre   <<<960 + 2758, 384, 0, stream>>>(x_num, wih, bih, whh, c2w, fc1w, c1w, c1b, fc2w,
                                             GI, whhf, wprep, wfc1, w1h, fc2wT);
    k_mega  <<<2 * NIMG + 1, 512, SMEM_BYTES, stream>>>(x_img, w1h, c2b, wprep,
                                                        GI, whhf, bhh, pool2, hlast);
    k_fc1   <<<50 * 16, 256, 0, stream>>>(pool2, wfc1, part);
    k_post  <<<NIMG, 64, 0, stream>>>(part, fc1b, fbw, fbb, fc2wT, fc2b, out, fc2o);
    k_final <<<NBATCH, 256, 0, stream>>>(hlast, fc2o, gw, gb, fw, fb, finw, finb, out);
}